// Round 3
// baseline (717.610 us; speedup 1.0000x reference)
//
#include <hip/hip_runtime.h>

#define B_DIM 16
#define U_DIM 1024
#define H_DIM 8
#define S_DIM 1024
#define C_DIM 128
#define KD 1024  // K depth of both projection GEMMs
#define SCALE 0.08838834764831845f  // 1/sqrt(128)

typedef __attribute__((ext_vector_type(8))) short s16x8;
typedef __attribute__((ext_vector_type(4))) float f32x4;

__device__ __forceinline__ void gll16(const void* g, void* l) {
  __builtin_amdgcn_global_load_lds(
      (const __attribute__((address_space(1))) unsigned int*)g,
      (__attribute__((address_space(3))) unsigned int*)l, 16, 0, 0);
}
__device__ __forceinline__ unsigned short f2bf(float f) {
  unsigned u = __float_as_uint(f);
  u += 0x7FFF + ((u >> 16) & 1u);
  return (unsigned short)(u >> 16);
}
#define MFMA16(a, b, c) __builtin_amdgcn_mfma_f32_16x16x32_bf16(a, b, c, 0, 0, 0)

// ---------------------------------------------------------------------------
// Mask storage detection (bool may arrive as u8 / i32 / f32). See R1 notes.
// ---------------------------------------------------------------------------
__global__ void detect_mask(const unsigned char* __restrict__ mask_raw, int* __restrict__ flag) {
  __shared__ int not01, notf;
  if (threadIdx.x == 0) { not01 = 0; notf = 0; }
  __syncthreads();
  const unsigned int* p = (const unsigned int*)mask_raw;
  int l01 = 0, lf = 0;
  for (int i = threadIdx.x; i < 4096; i += 256) {
    unsigned int v = p[i];
    if (v != 0u && v != 1u) l01 = 1;
    if (v != 0u && v != 0x3F800000u) lf = 1;
  }
  if (l01) atomicOr(&not01, 1);
  if (lf) atomicOr(&notf, 1);
  __syncthreads();
  if (threadIdx.x == 0) flag[0] = (!not01) ? 0 : ((!notf) ? 2 : 1);
}

// invm[b,q] = (rowsum>0) ? SCALE/rowsum : 0
__global__ __launch_bounds__(256) void mask_invm(const unsigned char* __restrict__ mask_raw,
                                                 const int* __restrict__ flag,
                                                 float* __restrict__ invm) {
  int row = blockIdx.x * 4 + (threadIdx.x >> 6);
  int lane = threadIdx.x & 63;
  int mkind = flag[0];
  int sum = 0;
  if (mkind == 1) {
    const unsigned char* p = mask_raw + (size_t)row * S_DIM;
    for (int k = lane; k < S_DIM; k += 64) sum += (p[k] != 0);
  } else if (mkind == 0) {
    const int* p = (const int*)mask_raw + (size_t)row * S_DIM;
    for (int k = lane; k < S_DIM; k += 64) sum += (p[k] != 0);
  } else {
    const float* p = (const float*)mask_raw + (size_t)row * S_DIM;
    for (int k = lane; k < S_DIM; k += 64) sum += (p[k] != 0.f);
  }
#pragma unroll
  for (int off = 32; off > 0; off >>= 1) sum += __shfl_down(sum, off, 64);
  if (lane == 0) invm[row] = (sum > 0) ? (SCALE / (float)sum) : 0.f;
}

// ---------------------------------------------------------------------------
// Pack mask into transposed bit-words: bits[(b*S + k)*16 + q/64] bit (q&63).
// Grid (S/64 ktile, S/64 qword, B), block 256. LDS tile + __ballot.
// ---------------------------------------------------------------------------
__global__ __launch_bounds__(256) void pack_mask(const unsigned char* __restrict__ mask_raw,
                                                 const int* __restrict__ flag,
                                                 unsigned long long* __restrict__ bits) {
  __shared__ unsigned char tile[64][80];  // [q][k], pad 80 keeps 16B alignment
  const int t = threadIdx.x;
  const int kt = blockIdx.x * 64, qw = blockIdx.y, b = blockIdx.z;
  const int mk = flag[0];
  const int q = t >> 2, kbase = (t & 3) * 16;
  const size_t row = (size_t)(b * S_DIM + qw * 64 + q);
  if (mk == 1) {
    uint4 v = *(const uint4*)(mask_raw + (row << 10) + kt + kbase);
    *(uint4*)&tile[q][kbase] = v;
  } else if (mk == 0) {
    const int* p = (const int*)mask_raw + (row << 10) + kt + kbase;
#pragma unroll
    for (int j = 0; j < 4; ++j) {
      int4 v = ((const int4*)p)[j];
      uchar4 o;
      o.x = v.x ? 1 : 0; o.y = v.y ? 1 : 0; o.z = v.z ? 1 : 0; o.w = v.w ? 1 : 0;
      *(uchar4*)&tile[q][kbase + j * 4] = o;
    }
  } else {
    const float* p = (const float*)mask_raw + (row << 10) + kt + kbase;
#pragma unroll
    for (int j = 0; j < 4; ++j) {
      float4 v = ((const float4*)p)[j];
      uchar4 o;
      o.x = (v.x != 0.f) ? 1 : 0; o.y = (v.y != 0.f) ? 1 : 0;
      o.z = (v.z != 0.f) ? 1 : 0; o.w = (v.w != 0.f) ? 1 : 0;
      *(uchar4*)&tile[q][kbase + j * 4] = o;
    }
  }
  __syncthreads();
  const int wave = t >> 6, lane = t & 63;
#pragma unroll
  for (int kk = 0; kk < 16; ++kk) {
    int k = wave * 16 + kk;
    unsigned long long bal = __ballot(tile[lane][k] != 0);
    if (lane == 0) bits[((size_t)(b * S_DIM + kt + k) << 4) + qw] = bal;
  }
}

// fp32 -> bf16 elementwise (weights)
__global__ __launch_bounds__(256) void cvt_bf16(const float* __restrict__ in,
                                                unsigned short* __restrict__ out, int n) {
  int i = (blockIdx.x * 256 + threadIdx.x) * 4;
  if (i < n) {
    float4 v = *(const float4*)(in + i);
    ushort4 o;
    o.x = f2bf(v.x); o.y = f2bf(v.y); o.z = f2bf(v.z); o.w = f2bf(v.w);
    *(ushort4*)(out + i) = o;
  }
}

// x[b][u][s] f32 -> xT[b][s][u] bf16   (32x32 tiles)
__global__ __launch_bounds__(256) void transpose_x(const float* __restrict__ x,
                                                   unsigned short* __restrict__ xT) {
  __shared__ float T[32][33];
  const int t = threadIdx.x, r = t >> 3, c4 = (t & 7) * 4;
  const int s0 = blockIdx.x * 32, u0 = blockIdx.y * 32;
  const size_t base = (size_t)blockIdx.z * U_DIM * S_DIM;
  float4 v = *(const float4*)(x + base + (size_t)(u0 + r) * S_DIM + s0 + c4);
  T[r][c4 + 0] = v.x; T[r][c4 + 1] = v.y; T[r][c4 + 2] = v.z; T[r][c4 + 3] = v.w;
  __syncthreads();
  ushort4 o;
  o.x = f2bf(T[c4 + 0][r]); o.y = f2bf(T[c4 + 1][r]);
  o.z = f2bf(T[c4 + 2][r]); o.w = f2bf(T[c4 + 3][r]);
  *(ushort4*)(xT + base + (size_t)(s0 + r) * U_DIM + u0 + c4) = o;
}

// qkvT[b][k][2048+c] bf16 -> VT[b][c][k] bf16  (32x32 tiles)
__global__ __launch_bounds__(256) void transpose_v(const unsigned short* __restrict__ qkvT,
                                                   unsigned short* __restrict__ VT) {
  __shared__ unsigned short T[32][34];
  const int t = threadIdx.x, r = t >> 3, c4 = (t & 7) * 4;
  const int k0 = blockIdx.x * 32, c0 = blockIdx.y * 32;
  const unsigned short* qb = qkvT + (size_t)blockIdx.z * S_DIM * (3 * U_DIM);
  ushort4 v = *(const ushort4*)(qb + (size_t)(k0 + r) * (3 * U_DIM) + 2 * U_DIM + c0 + c4);
  T[r][c4 + 0] = v.x; T[r][c4 + 1] = v.y; T[r][c4 + 2] = v.z; T[r][c4 + 3] = v.w;
  __syncthreads();
  ushort4 o;
  o.x = T[c4 + 0][r]; o.y = T[c4 + 1][r]; o.z = T[c4 + 2][r]; o.w = T[c4 + 3][r];
  *(ushort4*)(VT + (size_t)blockIdx.z * U_DIM * S_DIM + (size_t)(c0 + r) * S_DIM + k0 + c4) = o;
}

// ---------------------------------------------------------------------------
// bf16 MFMA GEMM (m97 structure + XOR-swizzled LDS chunks):
//   D[m][n] = sum_k A[m][k] * B[n][k];  A,B row-major with K=1024 contiguous.
// ---------------------------------------------------------------------------
template <typename OUT>
__global__ __launch_bounds__(256) void gemm_tt(const unsigned short* __restrict__ A,
                                               const unsigned short* __restrict__ Bm,
                                               OUT* __restrict__ D,
                                               long long sAb, long long sBb, long long sDb,
                                               int N) {
  __shared__ unsigned short sA[128 * 32];
  __shared__ unsigned short sB[128 * 32];
  const int tid = threadIdx.x, wave = tid >> 6, lane = tid & 63;
  const int l15 = lane & 15, quad = lane >> 4;
  const int m0 = blockIdx.y * 128, n0 = blockIdx.x * 128;
  A += (size_t)blockIdx.z * sAb;
  Bm += (size_t)blockIdx.z * sBb;
  D += (size_t)blockIdx.z * sDb;
  const int wm = (wave >> 1) * 64, wn = (wave & 1) * 64;
  f32x4 acc[4][4] = {};

  for (int k0 = 0; k0 < KD; k0 += 32) {
#pragma unroll
    for (int t = 0; t < 2; ++t) {
      int p = wave * 128 + t * 64 + lane;
      int row = p >> 2, kc = (p & 3) ^ (row & 3);
      gll16(A + (size_t)(m0 + row) * KD + k0 + kc * 8, &sA[(wave * 128 + t * 64) * 8]);
    }
#pragma unroll
    for (int t = 0; t < 2; ++t) {
      int p = wave * 128 + t * 64 + lane;
      int row = p >> 2, kc = (p & 3) ^ (row & 3);
      gll16(Bm + (size_t)(n0 + row) * KD + k0 + kc * 8, &sB[(wave * 128 + t * 64) * 8]);
    }
    __syncthreads();
    s16x8 af[4], bf[4];
#pragma unroll
    for (int i = 0; i < 4; ++i) {
      int row = wm + i * 16 + l15;
      af[i] = *(const s16x8*)&sA[row * 32 + (quad ^ (row & 3)) * 8];
    }
#pragma unroll
    for (int j = 0; j < 4; ++j) {
      int row = wn + j * 16 + l15;
      bf[j] = *(const s16x8*)&sB[row * 32 + (quad ^ (row & 3)) * 8];
    }
#pragma unroll
    for (int i = 0; i < 4; ++i)
#pragma unroll
      for (int j = 0; j < 4; ++j) acc[i][j] = MFMA16(af[i], bf[j], acc[i][j]);
    __syncthreads();
  }
#pragma unroll
  for (int i = 0; i < 4; ++i)
#pragma unroll
    for (int j = 0; j < 4; ++j) {
      f32x4 v = acc[i][j];
#pragma unroll
      for (int r = 0; r < 4; ++r) {
        int m = m0 + wm + i * 16 + quad * 4 + r;
        int n = n0 + wn + j * 16 + l15;
        if constexpr (sizeof(OUT) == 2) D[(size_t)m * N + n] = f2bf(v[r]);
        else D[(size_t)m * N + n] = v[r];
      }
    }
}

// ---------------------------------------------------------------------------
// Fused masked-relu attention, bf16 MFMA, packed bitmask, Qs/Ps LDS aliased.
// Block = (q-tile 64, head, batch). K-tiles of 64.
// ---------------------------------------------------------------------------
__global__ __launch_bounds__(256, 3) void attn_mfma(const unsigned short* __restrict__ qkvT,
                                                    const unsigned short* __restrict__ VT,
                                                    const unsigned long long* __restrict__ bits,
                                                    const float* __restrict__ invm,
                                                    unsigned short* __restrict__ CcT, int b0) {
  __shared__ unsigned short Ks[64 * 128];   // [k][c] swizzled (16 KB)
  __shared__ unsigned short Vs[128 * 64];   // [c][k] swizzled (16 KB)
  __shared__ unsigned short QPs[64 * 128];  // Q staging, then Ps [q][k] (16 KB)
  __shared__ float invs[64];

  const int tid = threadIdx.x, wave = tid >> 6, lane = tid & 63;
  const int l15 = lane & 15, quad = lane >> 4;
  const int q0 = blockIdx.x * 64, h = blockIdx.y, z = blockIdx.z, b = b0 + z;
  const unsigned short* qB = qkvT + (size_t)z * S_DIM * (3 * U_DIM);
  const unsigned short* Vb = VT + (size_t)z * U_DIM * S_DIM + (size_t)h * C_DIM * S_DIM;
  const unsigned long long* mb = bits + ((size_t)b * S_DIM << 4) + (q0 >> 6);

  // stage Q tile (64 rows x 16 chunks, chunk ^= row&7)
#pragma unroll
  for (int t = 0; t < 4; ++t) {
    int p = wave * 256 + t * 64 + lane;
    int row = p >> 4, c = (p & 15) ^ (row & 7);
    gll16(qB + (size_t)(q0 + row) * (3 * U_DIM) + h * C_DIM + c * 8,
          &QPs[(wave * 256 + t * 64) * 8]);
  }
  if (tid < 64) invs[tid] = invm[(size_t)b * S_DIM + q0 + tid];
  __syncthreads();

  // Q fragments + invm to registers; QPs is then reusable as Ps
  s16x8 qf[4][4];
#pragma unroll
  for (int i = 0; i < 4; ++i)
#pragma unroll
    for (int kk = 0; kk < 4; ++kk) {
      int row = i * 16 + l15;
      qf[i][kk] = *(const s16x8*)&QPs[row * 128 + ((kk * 4 + quad) ^ (row & 7)) * 8];
    }
  float invf[4][4];
#pragma unroll
  for (int i = 0; i < 4; ++i)
#pragma unroll
    for (int r = 0; r < 4; ++r) invf[i][r] = invs[i * 16 + quad * 4 + r];

  f32x4 pacc[4][2] = {};

  for (int kt = 0; kt < S_DIM / 64; ++kt) {
    const int k0t = kt * 64;
    __syncthreads();  // prev PV done (Ks/Vs/QPs free)
    // stage K tile
#pragma unroll
    for (int t = 0; t < 4; ++t) {
      int p = wave * 256 + t * 64 + lane;
      int row = p >> 4, c = (p & 15) ^ (row & 7);
      gll16(qB + (size_t)(k0t + row) * (3 * U_DIM) + U_DIM + h * C_DIM + c * 8,
            &Ks[(wave * 256 + t * 64) * 8]);
    }
    // stage V tile ([c][k], 128 rows x 8 chunks)
#pragma unroll
    for (int t = 0; t < 4; ++t) {
      int p = wave * 256 + t * 64 + lane;
      int row = p >> 3, kc = (p & 7) ^ (row & 7);
      gll16(Vb + (size_t)row * S_DIM + k0t + kc * 8, &Vs[(wave * 256 + t * 64) * 8]);
    }
    // one packed mask word: 16 q bits at this thread's k column
    unsigned long long w64 = mb[(size_t)(k0t + wave * 16 + l15) << 4];
    __syncthreads();  // K/V tiles ready

    // scores: wave handles k-cols [wave*16, wave*16+16), all 64 q rows
    f32x4 sacc[4] = {};
#pragma unroll
    for (int kk = 0; kk < 4; ++kk) {
      int row = wave * 16 + l15;
      s16x8 bk = *(const s16x8*)&Ks[row * 128 + ((kk * 4 + quad) ^ (row & 7)) * 8];
#pragma unroll
      for (int i = 0; i < 4; ++i) sacc[i] = MFMA16(qf[i][kk], bk, sacc[i]);
    }
    // P = maskbit * relu(s) * scale/m  -> bf16 -> LDS (swizzled [q][k])
#pragma unroll
    for (int i = 0; i < 4; ++i)
#pragma unroll
      for (int r = 0; r < 4; ++r) {
        int q = i * 16 + quad * 4 + r;
        int kl = wave * 16 + l15;
        float p = fmaxf(sacc[i][r], 0.f) * invf[i][r];
        p = ((w64 >> q) & 1ull) ? p : 0.f;
        QPs[q * 64 + (((kl >> 3) ^ (q & 7))) * 8 + (kl & 7)] = f2bf(p);
      }
    __syncthreads();  // P ready

    // PV: wave handles c-cols [wave*32, wave*32+32)
#pragma unroll
    for (int ks = 0; ks < 2; ++ks) {
      s16x8 pf[4], vf[2];
#pragma unroll
      for (int i = 0; i < 4; ++i) {
        int row = i * 16 + l15;
        pf[i] = *(const s16x8*)&QPs[row * 64 + ((ks * 4 + quad) ^ (row & 7)) * 8];
      }
#pragma unroll
      for (int j = 0; j < 2; ++j) {
        int row = wave * 32 + j * 16 + l15;
        vf[j] = *(const s16x8*)&Vs[row * 64 + ((ks * 4 + quad) ^ (row & 7)) * 8];
      }
#pragma unroll
      for (int i = 0; i < 4; ++i)
#pragma unroll
        for (int j = 0; j < 2; ++j) pacc[i][j] = MFMA16(pf[i], vf[j], pacc[i][j]);
    }
  }

  // epilogue: CcT[b][q][h*128+c] bf16
  unsigned short* cb = CcT + (size_t)z * S_DIM * U_DIM;
#pragma unroll
  for (int i = 0; i < 4; ++i)
#pragma unroll
    for (int j = 0; j < 2; ++j) {
      f32x4 v = pacc[i][j];
#pragma unroll
      for (int r = 0; r < 4; ++r) {
        int q = q0 + i * 16 + quad * 4 + r;
        int c = h * C_DIM + wave * 32 + j * 16 + l15;
        cb[(size_t)q * U_DIM + c] = f2bf(v[r]);
      }
    }
}

// ---------------------------------------------------------------------------
extern "C" void kernel_launch(void* const* d_in, const int* in_sizes, int n_in,
                              void* d_out, int out_size, void* d_ws, size_t ws_size,
                              hipStream_t stream) {
  const float* x = (const float*)d_in[0];
  const unsigned char* mask_raw = (const unsigned char*)d_in[1];
  const float* w_qkv = (const float*)d_in[2];
  const float* w_out = (const float*)d_in[3];
  float* out = (float*)d_out;

  char* ws = (char*)d_ws;
  int* flag = (int*)ws;                                  // 256 B
  float* invm = (float*)(ws + 256);                      // 64 KB
  unsigned long long* bits = (unsigned long long*)(ws + 256 + 65536);  // 2 MB
  unsigned short* wqkv_bf = (unsigned short*)((char*)bits + (size_t)B_DIM * S_DIM * 16 * 8);
  unsigned short* wout_bf = (unsigned short*)((char*)wqkv_bf + (size_t)3 * U_DIM * U_DIM * 2);
  char* heap = (char*)wout_bf + (size_t)U_DIM * U_DIM * 2;

  const size_t xT_pb = (size_t)U_DIM * S_DIM * 2;
  const size_t qkvT_pb = (size_t)3 * U_DIM * S_DIM * 2;
  const size_t vT_pb = (size_t)U_DIM * S_DIM * 2;
  const size_t ccT_pb = (size_t)U_DIM * S_DIM * 2;
  const size_t per_batch = xT_pb + qkvT_pb + vT_pb + ccT_pb;  // 12.58 MB
  const size_t fixed = (size_t)(heap - ws);
  int nb = (ws_size > fixed) ? (int)((ws_size - fixed) / per_batch) : 1;
  if (nb < 1) nb = 1;
  if (nb > B_DIM) nb = B_DIM;

  unsigned short* xT = (unsigned short*)heap;
  unsigned short* qkvT = (unsigned short*)(heap + (size_t)nb * xT_pb);
  unsigned short* VT = (unsigned short*)(heap + (size_t)nb * (xT_pb + qkvT_pb));
  unsigned short* CcT = (unsigned short*)(heap + (size_t)nb * (xT_pb + qkvT_pb + vT_pb));

  detect_mask<<<1, 256, 0, stream>>>(mask_raw, flag);
  mask_invm<<<(B_DIM * S_DIM) / 4, 256, 0, stream>>>(mask_raw, flag, invm);
  pack_mask<<<dim3(S_DIM / 64, S_DIM / 64, B_DIM), 256, 0, stream>>>(mask_raw, flag, bits);
  cvt_bf16<<<(3 * U_DIM * U_DIM) / 1024, 256, 0, stream>>>(w_qkv, wqkv_bf, 3 * U_DIM * U_DIM);
  cvt_bf16<<<(U_DIM * U_DIM) / 1024, 256, 0, stream>>>(w_out, wout_bf, U_DIM * U_DIM);

  for (int b0 = 0; b0 < B_DIM; b0 += nb) {
    int cnt = (B_DIM - b0 < nb) ? (B_DIM - b0) : nb;
    transpose_x<<<dim3(S_DIM / 32, U_DIM / 32, cnt), 256, 0, stream>>>(
        x + (size_t)b0 * U_DIM * S_DIM, xT);
    gemm_tt<unsigned short><<<dim3(3 * U_DIM / 128, S_DIM / 128, cnt), 256, 0, stream>>>(
        xT, wqkv_bf, qkvT, (long long)U_DIM * S_DIM, 0LL, (long long)3 * U_DIM * S_DIM, 3 * U_DIM);
    transpose_v<<<dim3(S_DIM / 32, U_DIM / 32, cnt), 256, 0, stream>>>(qkvT, VT);
    attn_mfma<<<dim3(S_DIM / 64, H_DIM, cnt), 256, 0, stream>>>(
        qkvT, VT, bits, invm, CcT, b0);
    gemm_tt<float><<<dim3(S_DIM / 128, U_DIM / 128, cnt), 256, 0, stream>>>(
        wout_bf, CcT, out + (size_t)b0 * U_DIM * S_DIM, 0LL,
        (long long)U_DIM * S_DIM, (long long)U_DIM * S_DIM, S_DIM);
  }
}

// Round 4
// 673.073 us; speedup vs baseline: 1.0662x; 1.0662x over previous
//
#include <hip/hip_runtime.h>

#define B_DIM 16
#define U_DIM 1024
#define H_DIM 8
#define S_DIM 1024
#define C_DIM 128
#define KD 1024  // K depth of both projection GEMMs
#define SCALE 0.08838834764831845f  // 1/sqrt(128)

typedef __attribute__((ext_vector_type(8))) short s16x8;
typedef __attribute__((ext_vector_type(4))) float f32x4;

__device__ __forceinline__ void gll16(const void* g, void* l) {
  __builtin_amdgcn_global_load_lds(
      (const __attribute__((address_space(1))) unsigned int*)g,
      (__attribute__((address_space(3))) unsigned int*)l, 16, 0, 0);
}
__device__ __forceinline__ unsigned short f2bf(float f) {
  unsigned u = __float_as_uint(f);
  u += 0x7FFF + ((u >> 16) & 1u);
  return (unsigned short)(u >> 16);
}
#define MFMA16(a, b, c) __builtin_amdgcn_mfma_f32_16x16x32_bf16(a, b, c, 0, 0, 0)

// ---------------------------------------------------------------------------
// Mask storage detection (bool may arrive as u8 / i32 / f32). See R1 notes.
// ---------------------------------------------------------------------------
__global__ void detect_mask(const unsigned char* __restrict__ mask_raw, int* __restrict__ flag) {
  __shared__ int not01, notf;
  if (threadIdx.x == 0) { not01 = 0; notf = 0; }
  __syncthreads();
  const unsigned int* p = (const unsigned int*)mask_raw;
  int l01 = 0, lf = 0;
  for (int i = threadIdx.x; i < 4096; i += 256) {
    unsigned int v = p[i];
    if (v != 0u && v != 1u) l01 = 1;
    if (v != 0u && v != 0x3F800000u) lf = 1;
  }
  if (l01) atomicOr(&not01, 1);
  if (lf) atomicOr(&notf, 1);
  __syncthreads();
  if (threadIdx.x == 0) flag[0] = (!not01) ? 0 : ((!notf) ? 2 : 1);
}

// invm[b,q] = (rowsum>0) ? SCALE/rowsum : 0
__global__ __launch_bounds__(256) void mask_invm(const unsigned char* __restrict__ mask_raw,
                                                 const int* __restrict__ flag,
                                                 float* __restrict__ invm) {
  int row = blockIdx.x * 4 + (threadIdx.x >> 6);
  int lane = threadIdx.x & 63;
  int mkind = flag[0];
  int sum = 0;
  if (mkind == 1) {
    const unsigned char* p = mask_raw + (size_t)row * S_DIM;
    for (int k = lane; k < S_DIM; k += 64) sum += (p[k] != 0);
  } else if (mkind == 0) {
    const int* p = (const int*)mask_raw + (size_t)row * S_DIM;
    for (int k = lane; k < S_DIM; k += 64) sum += (p[k] != 0);
  } else {
    const float* p = (const float*)mask_raw + (size_t)row * S_DIM;
    for (int k = lane; k < S_DIM; k += 64) sum += (p[k] != 0.f);
  }
#pragma unroll
  for (int off = 32; off > 0; off >>= 1) sum += __shfl_down(sum, off, 64);
  if (lane == 0) invm[row] = (sum > 0) ? (SCALE / (float)sum) : 0.f;
}

// ---------------------------------------------------------------------------
// Pack mask into bit-words, layout bits[qw][b][k] (qw = q/64, bit = q&63).
// A wave in attn then reads 16 CONSECUTIVE u64s (one 128B line) per k-tile.
// ---------------------------------------------------------------------------
__global__ __launch_bounds__(256) void pack_mask(const unsigned char* __restrict__ mask_raw,
                                                 const int* __restrict__ flag,
                                                 unsigned long long* __restrict__ bits) {
  __shared__ unsigned char tile[64][80];  // [q][k], pad 80 keeps 16B alignment
  const int t = threadIdx.x;
  const int kt = blockIdx.x * 64, qw = blockIdx.y, b = blockIdx.z;
  const int mk = flag[0];
  const int q = t >> 2, kbase = (t & 3) * 16;
  const size_t row = (size_t)(b * S_DIM + qw * 64 + q);
  if (mk == 1) {
    uint4 v = *(const uint4*)(mask_raw + (row << 10) + kt + kbase);
    *(uint4*)&tile[q][kbase] = v;
  } else if (mk == 0) {
    const int* p = (const int*)mask_raw + (row << 10) + kt + kbase;
#pragma unroll
    for (int j = 0; j < 4; ++j) {
      int4 v = ((const int4*)p)[j];
      uchar4 o;
      o.x = v.x ? 1 : 0; o.y = v.y ? 1 : 0; o.z = v.z ? 1 : 0; o.w = v.w ? 1 : 0;
      *(uchar4*)&tile[q][kbase + j * 4] = o;
    }
  } else {
    const float* p = (const float*)mask_raw + (row << 10) + kt + kbase;
#pragma unroll
    for (int j = 0; j < 4; ++j) {
      float4 v = ((const float4*)p)[j];
      uchar4 o;
      o.x = (v.x != 0.f) ? 1 : 0; o.y = (v.y != 0.f) ? 1 : 0;
      o.z = (v.z != 0.f) ? 1 : 0; o.w = (v.w != 0.f) ? 1 : 0;
      *(uchar4*)&tile[q][kbase + j * 4] = o;
    }
  }
  __syncthreads();
  const int wave = t >> 6, lane = t & 63;
#pragma unroll
  for (int kk = 0; kk < 16; ++kk) {
    int k = wave * 16 + kk;
    unsigned long long bal = __ballot(tile[lane][k] != 0);
    if (lane == 0)
      bits[(size_t)qw * (B_DIM * S_DIM) + (size_t)b * S_DIM + kt + k] = bal;
  }
}

// fp32 -> bf16 elementwise (weights)
__global__ __launch_bounds__(256) void cvt_bf16(const float* __restrict__ in,
                                                unsigned short* __restrict__ out, int n) {
  int i = (blockIdx.x * 256 + threadIdx.x) * 4;
  if (i < n) {
    float4 v = *(const float4*)(in + i);
    ushort4 o;
    o.x = f2bf(v.x); o.y = f2bf(v.y); o.z = f2bf(v.z); o.w = f2bf(v.w);
    *(ushort4*)(out + i) = o;
  }
}

// x[b][u][s] f32 -> xT[b][s][u] bf16   (32x32 tiles)
__global__ __launch_bounds__(256) void transpose_x(const float* __restrict__ x,
                                                   unsigned short* __restrict__ xT) {
  __shared__ float T[32][33];
  const int t = threadIdx.x, r = t >> 3, c4 = (t & 7) * 4;
  const int s0 = blockIdx.x * 32, u0 = blockIdx.y * 32;
  const size_t base = (size_t)blockIdx.z * U_DIM * S_DIM;
  float4 v = *(const float4*)(x + base + (size_t)(u0 + r) * S_DIM + s0 + c4);
  T[r][c4 + 0] = v.x; T[r][c4 + 1] = v.y; T[r][c4 + 2] = v.z; T[r][c4 + 3] = v.w;
  __syncthreads();
  ushort4 o;
  o.x = f2bf(T[c4 + 0][r]); o.y = f2bf(T[c4 + 1][r]);
  o.z = f2bf(T[c4 + 2][r]); o.w = f2bf(T[c4 + 3][r]);
  *(ushort4*)(xT + base + (size_t)(s0 + r) * U_DIM + u0 + c4) = o;
}

// qkvT[b][k][2048+c] bf16 -> VT[b][c][k] bf16  (32x32 tiles)
__global__ __launch_bounds__(256) void transpose_v(const unsigned short* __restrict__ qkvT,
                                                   unsigned short* __restrict__ VT) {
  __shared__ unsigned short T[32][34];
  const int t = threadIdx.x, r = t >> 3, c4 = (t & 7) * 4;
  const int k0 = blockIdx.x * 32, c0 = blockIdx.y * 32;
  const unsigned short* qb = qkvT + (size_t)blockIdx.z * S_DIM * (3 * U_DIM);
  ushort4 v = *(const ushort4*)(qb + (size_t)(k0 + r) * (3 * U_DIM) + 2 * U_DIM + c0 + c4);
  T[r][c4 + 0] = v.x; T[r][c4 + 1] = v.y; T[r][c4 + 2] = v.z; T[r][c4 + 3] = v.w;
  __syncthreads();
  ushort4 o;
  o.x = T[c4 + 0][r]; o.y = T[c4 + 1][r]; o.z = T[c4 + 2][r]; o.w = T[c4 + 3][r];
  *(ushort4*)(VT + (size_t)blockIdx.z * U_DIM * S_DIM + (size_t)(c0 + r) * S_DIM + k0 + c4) = o;
}

// ---------------------------------------------------------------------------
// bf16 MFMA GEMM (m97 structure + XOR-swizzled LDS chunks):
//   D[m][n] = sum_k A[m][k] * B[n][k];  A,B row-major with K=1024 contiguous.
// ---------------------------------------------------------------------------
template <typename OUT>
__global__ __launch_bounds__(256) void gemm_tt(const unsigned short* __restrict__ A,
                                               const unsigned short* __restrict__ Bm,
                                               OUT* __restrict__ D,
                                               long long sAb, long long sBb, long long sDb,
                                               int N) {
  __shared__ unsigned short sA[128 * 32];
  __shared__ unsigned short sB[128 * 32];
  const int tid = threadIdx.x, wave = tid >> 6, lane = tid & 63;
  const int l15 = lane & 15, quad = lane >> 4;
  const int m0 = blockIdx.y * 128, n0 = blockIdx.x * 128;
  A += (size_t)blockIdx.z * sAb;
  Bm += (size_t)blockIdx.z * sBb;
  D += (size_t)blockIdx.z * sDb;
  const int wm = (wave >> 1) * 64, wn = (wave & 1) * 64;
  f32x4 acc[4][4] = {};

  for (int k0 = 0; k0 < KD; k0 += 32) {
#pragma unroll
    for (int t = 0; t < 2; ++t) {
      int p = wave * 128 + t * 64 + lane;
      int row = p >> 2, kc = (p & 3) ^ (row & 3);
      gll16(A + (size_t)(m0 + row) * KD + k0 + kc * 8, &sA[(wave * 128 + t * 64) * 8]);
    }
#pragma unroll
    for (int t = 0; t < 2; ++t) {
      int p = wave * 128 + t * 64 + lane;
      int row = p >> 2, kc = (p & 3) ^ (row & 3);
      gll16(Bm + (size_t)(n0 + row) * KD + k0 + kc * 8, &sB[(wave * 128 + t * 64) * 8]);
    }
    __syncthreads();
    s16x8 af[4], bf[4];
#pragma unroll
    for (int i = 0; i < 4; ++i) {
      int row = wm + i * 16 + l15;
      af[i] = *(const s16x8*)&sA[row * 32 + (quad ^ (row & 3)) * 8];
    }
#pragma unroll
    for (int j = 0; j < 4; ++j) {
      int row = wn + j * 16 + l15;
      bf[j] = *(const s16x8*)&sB[row * 32 + (quad ^ (row & 3)) * 8];
    }
#pragma unroll
    for (int i = 0; i < 4; ++i)
#pragma unroll
      for (int j = 0; j < 4; ++j) acc[i][j] = MFMA16(af[i], bf[j], acc[i][j]);
    __syncthreads();
  }
#pragma unroll
  for (int i = 0; i < 4; ++i)
#pragma unroll
    for (int j = 0; j < 4; ++j) {
      f32x4 v = acc[i][j];
#pragma unroll
      for (int r = 0; r < 4; ++r) {
        int m = m0 + wm + i * 16 + quad * 4 + r;
        int n = n0 + wn + j * 16 + l15;
        if constexpr (sizeof(OUT) == 2) D[(size_t)m * N + n] = f2bf(v[r]);
        else D[(size_t)m * N + n] = v[r];
      }
    }
}

// ---------------------------------------------------------------------------
// Fused masked-relu attention, bf16 MFMA, packed bitmask, XCD-aware swizzle.
// 1D grid of cnt*128 blocks; decode so all 16 q-tiles of one (h,b) pair land
// on one XCD (flat%8) and pairs walk sequentially per XCD -> K/V stays in L2.
// ---------------------------------------------------------------------------
__global__ __launch_bounds__(256, 3) void attn_mfma(const unsigned short* __restrict__ qkvT,
                                                    const unsigned short* __restrict__ VT,
                                                    const unsigned long long* __restrict__ bits,
                                                    const float* __restrict__ invm,
                                                    unsigned short* __restrict__ CcT,
                                                    int b0, int cnt) {
  __shared__ unsigned short Ks[64 * 128];   // [k][c] swizzled (16 KB)
  __shared__ unsigned short Vs[128 * 64];   // [c][k] swizzled (16 KB)
  __shared__ unsigned short QPs[64 * 128];  // Q staging, then Ps [q][k] (16 KB)
  __shared__ float invs[64];

  const int tid = threadIdx.x, wave = tid >> 6, lane = tid & 63;
  const int l15 = lane & 15, quad = lane >> 4;
  // XCD-locality decode: xcd = flat&7 owns pairs [xcd*cnt, xcd*cnt+cnt)
  const int flat = blockIdx.x;
  const int xcd = flat & 7, slot = flat >> 3;
  const int qt = slot & 15;
  const int pair = xcd * cnt + (slot >> 4);
  const int h = pair & 7, z = pair >> 3;
  const int q0 = qt * 64, b = b0 + z;

  const unsigned short* qB = qkvT + (size_t)z * S_DIM * (3 * U_DIM);
  const unsigned short* Vb = VT + (size_t)z * U_DIM * S_DIM + (size_t)h * C_DIM * S_DIM;
  const unsigned long long* mb = bits + (size_t)qt * (B_DIM * S_DIM) + (size_t)b * S_DIM;

  // stage Q tile (64 rows x 16 chunks, chunk ^= row&7)
#pragma unroll
  for (int t = 0; t < 4; ++t) {
    int p = wave * 256 + t * 64 + lane;
    int row = p >> 4, c = (p & 15) ^ (row & 7);
    gll16(qB + (size_t)(q0 + row) * (3 * U_DIM) + h * C_DIM + c * 8,
          &QPs[(wave * 256 + t * 64) * 8]);
  }
  if (tid < 64) invs[tid] = invm[(size_t)b * S_DIM + q0 + tid];
  __syncthreads();

  // Q fragments + invm to registers; QPs is then reusable as Ps
  s16x8 qf[4][4];
#pragma unroll
  for (int i = 0; i < 4; ++i)
#pragma unroll
    for (int kk = 0; kk < 4; ++kk) {
      int row = i * 16 + l15;
      qf[i][kk] = *(const s16x8*)&QPs[row * 128 + ((kk * 4 + quad) ^ (row & 7)) * 8];
    }
  float invf[4][4];
#pragma unroll
  for (int i = 0; i < 4; ++i)
#pragma unroll
    for (int r = 0; r < 4; ++r) invf[i][r] = invs[i * 16 + quad * 4 + r];

  f32x4 pacc[4][2] = {};

  for (int kt = 0; kt < S_DIM / 64; ++kt) {
    const int k0t = kt * 64;
    __syncthreads();  // prev PV done (Ks/Vs/QPs free)
    // stage K tile
#pragma unroll
    for (int t = 0; t < 4; ++t) {
      int p = wave * 256 + t * 64 + lane;
      int row = p >> 4, c = (p & 15) ^ (row & 7);
      gll16(qB + (size_t)(k0t + row) * (3 * U_DIM) + U_DIM + h * C_DIM + c * 8,
            &Ks[(wave * 256 + t * 64) * 8]);
    }
    // stage V tile ([c][k], 128 rows x 8 chunks)
#pragma unroll
    for (int t = 0; t < 4; ++t) {
      int p = wave * 256 + t * 64 + lane;
      int row = p >> 3, kc = (p & 7) ^ (row & 7);
      gll16(Vb + (size_t)row * S_DIM + k0t + kc * 8, &Vs[(wave * 256 + t * 64) * 8]);
    }
    // one packed mask word: 16 q bits at this thread's k column (coalesced:
    // 16 lanes read 16 consecutive u64s; quads broadcast)
    unsigned long long w64 = mb[k0t + wave * 16 + l15];
    __syncthreads();  // K/V tiles ready

    // scores: wave handles k-cols [wave*16, wave*16+16), all 64 q rows
    f32x4 sacc[4] = {};
#pragma unroll
    for (int kk = 0; kk < 4; ++kk) {
      int row = wave * 16 + l15;
      s16x8 bk = *(const s16x8*)&Ks[row * 128 + ((kk * 4 + quad) ^ (row & 7)) * 8];
#pragma unroll
      for (int i = 0; i < 4; ++i) sacc[i] = MFMA16(qf[i][kk], bk, sacc[i]);
    }
    // P = maskbit * relu(s) * scale/m  -> bf16 -> LDS (swizzled [q][k])
#pragma unroll
    for (int i = 0; i < 4; ++i)
#pragma unroll
      for (int r = 0; r < 4; ++r) {
        int q = i * 16 + quad * 4 + r;
        int kl = wave * 16 + l15;
        float p = fmaxf(sacc[i][r], 0.f) * invf[i][r];
        p = ((w64 >> q) & 1ull) ? p : 0.f;
        QPs[q * 64 + (((kl >> 3) ^ (q & 7))) * 8 + (kl & 7)] = f2bf(p);
      }
    __syncthreads();  // P ready

    // PV: wave handles c-cols [wave*32, wave*32+32)
#pragma unroll
    for (int ks = 0; ks < 2; ++ks) {
      s16x8 pf[4], vf[2];
#pragma unroll
      for (int i = 0; i < 4; ++i) {
        int row = i * 16 + l15;
        pf[i] = *(const s16x8*)&QPs[row * 64 + ((ks * 4 + quad) ^ (row & 7)) * 8];
      }
#pragma unroll
      for (int j = 0; j < 2; ++j) {
        int row = wave * 32 + j * 16 + l15;
        vf[j] = *(const s16x8*)&Vs[row * 64 + ((ks * 4 + quad) ^ (row & 7)) * 8];
      }
#pragma unroll
      for (int i = 0; i < 4; ++i)
#pragma unroll
        for (int j = 0; j < 2; ++j) pacc[i][j] = MFMA16(pf[i], vf[j], pacc[i][j]);
    }
  }

  // epilogue: CcT[b][q][h*128+c] bf16
  unsigned short* cb = CcT + (size_t)z * S_DIM * U_DIM;
#pragma unroll
  for (int i = 0; i < 4; ++i)
#pragma unroll
    for (int j = 0; j < 2; ++j) {
      f32x4 v = pacc[i][j];
#pragma unroll
      for (int r = 0; r < 4; ++r) {
        int q = q0 + i * 16 + quad * 4 + r;
        int c = h * C_DIM + wave * 32 + j * 16 + l15;
        cb[(size_t)q * U_DIM + c] = f2bf(v[r]);
      }
    }
}

// ---------------------------------------------------------------------------
extern "C" void kernel_launch(void* const* d_in, const int* in_sizes, int n_in,
                              void* d_out, int out_size, void* d_ws, size_t ws_size,
                              hipStream_t stream) {
  const float* x = (const float*)d_in[0];
  const unsigned char* mask_raw = (const unsigned char*)d_in[1];
  const float* w_qkv = (const float*)d_in[2];
  const float* w_out = (const float*)d_in[3];
  float* out = (float*)d_out;

  char* ws = (char*)d_ws;
  int* flag = (int*)ws;                                  // 256 B
  float* invm = (float*)(ws + 256);                      // 64 KB
  unsigned long long* bits = (unsigned long long*)(ws + 256 + 65536);  // 2 MB
  unsigned short* wqkv_bf = (unsigned short*)((char*)bits + (size_t)B_DIM * S_DIM * 16 * 8);
  unsigned short* wout_bf = (unsigned short*)((char*)wqkv_bf + (size_t)3 * U_DIM * U_DIM * 2);
  char* heap = (char*)wout_bf + (size_t)U_DIM * U_DIM * 2;

  const size_t xT_pb = (size_t)U_DIM * S_DIM * 2;
  const size_t qkvT_pb = (size_t)3 * U_DIM * S_DIM * 2;
  const size_t vT_pb = (size_t)U_DIM * S_DIM * 2;
  const size_t ccT_pb = (size_t)U_DIM * S_DIM * 2;
  const size_t per_batch = xT_pb + qkvT_pb + vT_pb + ccT_pb;  // 12.58 MB
  const size_t fixed = (size_t)(heap - ws);
  int nb = (ws_size > fixed) ? (int)((ws_size - fixed) / per_batch) : 1;
  if (nb < 1) nb = 1;
  if (nb > B_DIM) nb = B_DIM;

  unsigned short* xT = (unsigned short*)heap;
  unsigned short* qkvT = (unsigned short*)(heap + (size_t)nb * xT_pb);
  unsigned short* VT = (unsigned short*)(heap + (size_t)nb * (xT_pb + qkvT_pb));
  unsigned short* CcT = (unsigned short*)(heap + (size_t)nb * (xT_pb + qkvT_pb + vT_pb));

  detect_mask<<<1, 256, 0, stream>>>(mask_raw, flag);
  mask_invm<<<(B_DIM * S_DIM) / 4, 256, 0, stream>>>(mask_raw, flag, invm);
  pack_mask<<<dim3(S_DIM / 64, S_DIM / 64, B_DIM), 256, 0, stream>>>(mask_raw, flag, bits);
  cvt_bf16<<<(3 * U_DIM * U_DIM) / 1024, 256, 0, stream>>>(w_qkv, wqkv_bf, 3 * U_DIM * U_DIM);
  cvt_bf16<<<(U_DIM * U_DIM) / 1024, 256, 0, stream>>>(w_out, wout_bf, U_DIM * U_DIM);

  for (int b0 = 0; b0 < B_DIM; b0 += nb) {
    int cnt = (B_DIM - b0 < nb) ? (B_DIM - b0) : nb;
    transpose_x<<<dim3(S_DIM / 32, U_DIM / 32, cnt), 256, 0, stream>>>(
        x + (size_t)b0 * U_DIM * S_DIM, xT);
    gemm_tt<unsigned short><<<dim3(3 * U_DIM / 128, S_DIM / 128, cnt), 256, 0, stream>>>(
        xT, wqkv_bf, qkvT, (long long)U_DIM * S_DIM, 0LL, (long long)3 * U_DIM * S_DIM, 3 * U_DIM);
    transpose_v<<<dim3(S_DIM / 32, U_DIM / 32, cnt), 256, 0, stream>>>(qkvT, VT);
    attn_mfma<<<dim3(cnt * 128), 256, 0, stream>>>(
        qkvT, VT, bits, invm, CcT, b0, cnt);
    gemm_tt<float><<<dim3(S_DIM / 128, U_DIM / 128, cnt), 256, 0, stream>>>(
        wout_bf, CcT, out + (size_t)b0 * U_DIM * S_DIM, 0LL,
        (long long)U_DIM * S_DIM, (long long)U_DIM * S_DIM, S_DIM);
  }
}

// Round 5
// 509.827 us; speedup vs baseline: 1.4076x; 1.3202x over previous
//
#include <hip/hip_runtime.h>

#define B_DIM 16
#define U_DIM 1024
#define H_DIM 8
#define S_DIM 1024
#define C_DIM 128
#define KD 1024  // K depth of both projection GEMMs
#define SCALE 0.08838834764831845f  // 1/sqrt(128)

typedef __attribute__((ext_vector_type(8))) short s16x8;
typedef __attribute__((ext_vector_type(4))) float f32x4;

__device__ __forceinline__ void gll16(const void* g, void* l) {
  __builtin_amdgcn_global_load_lds(
      (const __attribute__((address_space(1))) unsigned int*)g,
      (__attribute__((address_space(3))) unsigned int*)l, 16, 0, 0);
}
__device__ __forceinline__ unsigned short f2bf(float f) {
  unsigned u = __float_as_uint(f);
  u += 0x7FFF + ((u >> 16) & 1u);
  return (unsigned short)(u >> 16);
}
#define MFMA16(a, b, c) __builtin_amdgcn_mfma_f32_16x16x32_bf16(a, b, c, 0, 0, 0)

// ---------------------------------------------------------------------------
// Mask storage detection (bool may arrive as u8 / i32 / f32). See R1 notes.
// ---------------------------------------------------------------------------
__global__ void detect_mask(const unsigned char* __restrict__ mask_raw, int* __restrict__ flag) {
  __shared__ int not01, notf;
  if (threadIdx.x == 0) { not01 = 0; notf = 0; }
  __syncthreads();
  const unsigned int* p = (const unsigned int*)mask_raw;
  int l01 = 0, lf = 0;
  for (int i = threadIdx.x; i < 4096; i += 256) {
    unsigned int v = p[i];
    if (v != 0u && v != 1u) l01 = 1;
    if (v != 0u && v != 0x3F800000u) lf = 1;
  }
  if (l01) atomicOr(&not01, 1);
  if (lf) atomicOr(&notf, 1);
  __syncthreads();
  if (threadIdx.x == 0) flag[0] = (!not01) ? 0 : ((!notf) ? 2 : 1);
}

// invm[b,q] = (rowsum>0) ? SCALE/rowsum : 0
__global__ __launch_bounds__(256) void mask_invm(const unsigned char* __restrict__ mask_raw,
                                                 const int* __restrict__ flag,
                                                 float* __restrict__ invm) {
  int row = blockIdx.x * 4 + (threadIdx.x >> 6);
  int lane = threadIdx.x & 63;
  int mkind = flag[0];
  int sum = 0;
  if (mkind == 1) {
    const unsigned char* p = mask_raw + (size_t)row * S_DIM;
    for (int k = lane; k < S_DIM; k += 64) sum += (p[k] != 0);
  } else if (mkind == 0) {
    const int* p = (const int*)mask_raw + (size_t)row * S_DIM;
    for (int k = lane; k < S_DIM; k += 64) sum += (p[k] != 0);
  } else {
    const float* p = (const float*)mask_raw + (size_t)row * S_DIM;
    for (int k = lane; k < S_DIM; k += 64) sum += (p[k] != 0.f);
  }
#pragma unroll
  for (int off = 32; off > 0; off >>= 1) sum += __shfl_down(sum, off, 64);
  if (lane == 0) invm[row] = (sum > 0) ? (SCALE / (float)sum) : 0.f;
}

// ---------------------------------------------------------------------------
// Pack mask into bit-words, layout bits[qw][b][k] (qw = q/64, bit = q&63).
// A wave in attn then reads 16 CONSECUTIVE u64s (one 128B line) per k-tile.
// ---------------------------------------------------------------------------
__global__ __launch_bounds__(256) void pack_mask(const unsigned char* __restrict__ mask_raw,
                                                 const int* __restrict__ flag,
                                                 unsigned long long* __restrict__ bits) {
  __shared__ unsigned char tile[64][80];  // [q][k], pad 80 keeps 16B alignment
  const int t = threadIdx.x;
  const int kt = blockIdx.x * 64, qw = blockIdx.y, b = blockIdx.z;
  const int mk = flag[0];
  const int q = t >> 2, kbase = (t & 3) * 16;
  const size_t row = (size_t)(b * S_DIM + qw * 64 + q);
  if (mk == 1) {
    uint4 v = *(const uint4*)(mask_raw + (row << 10) + kt + kbase);
    *(uint4*)&tile[q][kbase] = v;
  } else if (mk == 0) {
    const int* p = (const int*)mask_raw + (row << 10) + kt + kbase;
#pragma unroll
    for (int j = 0; j < 4; ++j) {
      int4 v = ((const int4*)p)[j];
      uchar4 o;
      o.x = v.x ? 1 : 0; o.y = v.y ? 1 : 0; o.z = v.z ? 1 : 0; o.w = v.w ? 1 : 0;
      *(uchar4*)&tile[q][kbase + j * 4] = o;
    }
  } else {
    const float* p = (const float*)mask_raw + (row << 10) + kt + kbase;
#pragma unroll
    for (int j = 0; j < 4; ++j) {
      float4 v = ((const float4*)p)[j];
      uchar4 o;
      o.x = (v.x != 0.f) ? 1 : 0; o.y = (v.y != 0.f) ? 1 : 0;
      o.z = (v.z != 0.f) ? 1 : 0; o.w = (v.w != 0.f) ? 1 : 0;
      *(uchar4*)&tile[q][kbase + j * 4] = o;
    }
  }
  __syncthreads();
  const int wave = t >> 6, lane = t & 63;
#pragma unroll
  for (int kk = 0; kk < 16; ++kk) {
    int k = wave * 16 + kk;
    unsigned long long bal = __ballot(tile[lane][k] != 0);
    if (lane == 0)
      bits[(size_t)qw * (B_DIM * S_DIM) + (size_t)b * S_DIM + kt + k] = bal;
  }
}

// fp32 -> bf16 elementwise (weights)
__global__ __launch_bounds__(256) void cvt_bf16(const float* __restrict__ in,
                                                unsigned short* __restrict__ out, int n) {
  int i = (blockIdx.x * 256 + threadIdx.x) * 4;
  if (i < n) {
    float4 v = *(const float4*)(in + i);
    ushort4 o;
    o.x = f2bf(v.x); o.y = f2bf(v.y); o.z = f2bf(v.z); o.w = f2bf(v.w);
    *(ushort4*)(out + i) = o;
  }
}

// x[b][u][s] f32 -> xT[b][s][u] bf16   (32x32 tiles)
__global__ __launch_bounds__(256) void transpose_x(const float* __restrict__ x,
                                                   unsigned short* __restrict__ xT) {
  __shared__ float T[32][33];
  const int t = threadIdx.x, r = t >> 3, c4 = (t & 7) * 4;
  const int s0 = blockIdx.x * 32, u0 = blockIdx.y * 32;
  const size_t base = (size_t)blockIdx.z * U_DIM * S_DIM;
  float4 v = *(const float4*)(x + base + (size_t)(u0 + r) * S_DIM + s0 + c4);
  T[r][c4 + 0] = v.x; T[r][c4 + 1] = v.y; T[r][c4 + 2] = v.z; T[r][c4 + 3] = v.w;
  __syncthreads();
  ushort4 o;
  o.x = f2bf(T[c4 + 0][r]); o.y = f2bf(T[c4 + 1][r]);
  o.z = f2bf(T[c4 + 2][r]); o.w = f2bf(T[c4 + 3][r]);
  *(ushort4*)(xT + base + (size_t)(s0 + r) * U_DIM + u0 + c4) = o;
}

// qkvT[b][k][2048+c] bf16 -> VT[b][c][k] bf16  (32x32 tiles)
__global__ __launch_bounds__(256) void transpose_v(const unsigned short* __restrict__ qkvT,
                                                   unsigned short* __restrict__ VT) {
  __shared__ unsigned short T[32][34];
  const int t = threadIdx.x, r = t >> 3, c4 = (t & 7) * 4;
  const int k0 = blockIdx.x * 32, c0 = blockIdx.y * 32;
  const unsigned short* qb = qkvT + (size_t)blockIdx.z * S_DIM * (3 * U_DIM);
  ushort4 v = *(const ushort4*)(qb + (size_t)(k0 + r) * (3 * U_DIM) + 2 * U_DIM + c0 + c4);
  T[r][c4 + 0] = v.x; T[r][c4 + 1] = v.y; T[r][c4 + 2] = v.z; T[r][c4 + 3] = v.w;
  __syncthreads();
  ushort4 o;
  o.x = T[c4 + 0][r]; o.y = T[c4 + 1][r]; o.z = T[c4 + 2][r]; o.w = T[c4 + 3][r];
  *(ushort4*)(VT + (size_t)blockIdx.z * U_DIM * S_DIM + (size_t)(c0 + r) * S_DIM + k0 + c4) = o;
}

// ---------------------------------------------------------------------------
// bf16 MFMA GEMM (m97 structure + XOR-swizzled LDS chunks):
//   D[m][n] = sum_k A[m][k] * B[n][k];  A,B row-major with K=1024 contiguous.
// ---------------------------------------------------------------------------
template <typename OUT>
__global__ __launch_bounds__(256) void gemm_tt(const unsigned short* __restrict__ A,
                                               const unsigned short* __restrict__ Bm,
                                               OUT* __restrict__ D,
                                               long long sAb, long long sBb, long long sDb,
                                               int N) {
  __shared__ unsigned short sA[128 * 32];
  __shared__ unsigned short sB[128 * 32];
  const int tid = threadIdx.x, wave = tid >> 6, lane = tid & 63;
  const int l15 = lane & 15, quad = lane >> 4;
  const int m0 = blockIdx.y * 128, n0 = blockIdx.x * 128;
  A += (size_t)blockIdx.z * sAb;
  Bm += (size_t)blockIdx.z * sBb;
  D += (size_t)blockIdx.z * sDb;
  const int wm = (wave >> 1) * 64, wn = (wave & 1) * 64;
  f32x4 acc[4][4] = {};

  for (int k0 = 0; k0 < KD; k0 += 32) {
#pragma unroll
    for (int t = 0; t < 2; ++t) {
      int p = wave * 128 + t * 64 + lane;
      int row = p >> 2, kc = (p & 3) ^ (row & 3);
      gll16(A + (size_t)(m0 + row) * KD + k0 + kc * 8, &sA[(wave * 128 + t * 64) * 8]);
    }
#pragma unroll
    for (int t = 0; t < 2; ++t) {
      int p = wave * 128 + t * 64 + lane;
      int row = p >> 2, kc = (p & 3) ^ (row & 3);
      gll16(Bm + (size_t)(n0 + row) * KD + k0 + kc * 8, &sB[(wave * 128 + t * 64) * 8]);
    }
    __syncthreads();
    s16x8 af[4], bf[4];
#pragma unroll
    for (int i = 0; i < 4; ++i) {
      int row = wm + i * 16 + l15;
      af[i] = *(const s16x8*)&sA[row * 32 + (quad ^ (row & 3)) * 8];
    }
#pragma unroll
    for (int j = 0; j < 4; ++j) {
      int row = wn + j * 16 + l15;
      bf[j] = *(const s16x8*)&sB[row * 32 + (quad ^ (row & 3)) * 8];
    }
#pragma unroll
    for (int i = 0; i < 4; ++i)
#pragma unroll
      for (int j = 0; j < 4; ++j) acc[i][j] = MFMA16(af[i], bf[j], acc[i][j]);
    __syncthreads();
  }
#pragma unroll
  for (int i = 0; i < 4; ++i)
#pragma unroll
    for (int j = 0; j < 4; ++j) {
      f32x4 v = acc[i][j];
#pragma unroll
      for (int r = 0; r < 4; ++r) {
        int m = m0 + wm + i * 16 + quad * 4 + r;
        int n = n0 + wn + j * 16 + l15;
        if constexpr (sizeof(OUT) == 2) D[(size_t)m * N + n] = f2bf(v[r]);
        else D[(size_t)m * N + n] = v[r];
      }
    }
}

// ---------------------------------------------------------------------------
// Fused masked-relu attention, bf16 MFMA, packed coalesced bitmask.
// R2 structure: 3D grid (qt fastest), separate Qs/Ps buffers -> 56.5 KB LDS
// -> structurally 2 blocks/CU (the L2-friendly occupancy; 3/CU thrashed L2:
// R3/R4 showed FETCH x1.4-3 and WRITE x4 at occ 3).
// ---------------------------------------------------------------------------
__global__ __launch_bounds__(256, 2) void attn_mfma(const unsigned short* __restrict__ qkvT,
                                                    const unsigned short* __restrict__ VT,
                                                    const unsigned long long* __restrict__ bits,
                                                    const float* __restrict__ invm,
                                                    unsigned short* __restrict__ CcT, int b0) {
  __shared__ unsigned short Qs[64 * 128];  // [q][c] swizzled (16 KB)
  __shared__ unsigned short Ks[64 * 128];  // [k][c] swizzled (16 KB)
  __shared__ unsigned short Vs[128 * 64];  // [c][k] swizzled (16 KB)
  __shared__ unsigned short Ps[64 * 64];   // [q][k] swizzled (8 KB)
  __shared__ float invs[64];

  const int tid = threadIdx.x, wave = tid >> 6, lane = tid & 63;
  const int l15 = lane & 15, quad = lane >> 4;
  const int qt = blockIdx.x, h = blockIdx.y, z = blockIdx.z;
  const int q0 = qt * 64, b = b0 + z;
  const unsigned short* qB = qkvT + (size_t)z * S_DIM * (3 * U_DIM);
  const unsigned short* Vb = VT + (size_t)z * U_DIM * S_DIM + (size_t)h * C_DIM * S_DIM;
  const unsigned long long* mb = bits + (size_t)qt * (B_DIM * S_DIM) + (size_t)b * S_DIM;

  // stage Q tile (64 rows x 16 chunks, chunk ^= row&7)
#pragma unroll
  for (int t = 0; t < 4; ++t) {
    int p = wave * 256 + t * 64 + lane;
    int row = p >> 4, c = (p & 15) ^ (row & 7);
    gll16(qB + (size_t)(q0 + row) * (3 * U_DIM) + h * C_DIM + c * 8,
          &Qs[(wave * 256 + t * 64) * 8]);
  }
  if (tid < 64) invs[tid] = invm[(size_t)b * S_DIM + q0 + tid];
  __syncthreads();

  // Q fragments + invm to registers
  s16x8 qf[4][4];
#pragma unroll
  for (int i = 0; i < 4; ++i)
#pragma unroll
    for (int kk = 0; kk < 4; ++kk) {
      int row = i * 16 + l15;
      qf[i][kk] = *(const s16x8*)&Qs[row * 128 + ((kk * 4 + quad) ^ (row & 7)) * 8];
    }
  float invf[4][4];
#pragma unroll
  for (int i = 0; i < 4; ++i)
#pragma unroll
    for (int r = 0; r < 4; ++r) invf[i][r] = invs[i * 16 + quad * 4 + r];

  f32x4 pacc[4][2] = {};

  for (int kt = 0; kt < S_DIM / 64; ++kt) {
    const int k0t = kt * 64;
    __syncthreads();  // prev PV done (Ks/Vs free)
    // stage K tile
#pragma unroll
    for (int t = 0; t < 4; ++t) {
      int p = wave * 256 + t * 64 + lane;
      int row = p >> 4, c = (p & 15) ^ (row & 7);
      gll16(qB + (size_t)(k0t + row) * (3 * U_DIM) + U_DIM + h * C_DIM + c * 8,
            &Ks[(wave * 256 + t * 64) * 8]);
    }
    // stage V tile ([c][k], 128 rows x 8 chunks)
#pragma unroll
    for (int t = 0; t < 4; ++t) {
      int p = wave * 256 + t * 64 + lane;
      int row = p >> 3, kc = (p & 7) ^ (row & 7);
      gll16(Vb + (size_t)row * S_DIM + k0t + kc * 8, &Vs[(wave * 256 + t * 64) * 8]);
    }
    // one packed mask word: 16 q bits at this thread's k column (coalesced:
    // 16 lanes read 16 consecutive u64s = one 128B line; quads broadcast)
    unsigned long long w64 = mb[k0t + wave * 16 + l15];
    __syncthreads();  // K/V tiles ready

    // scores: wave handles k-cols [wave*16, wave*16+16), all 64 q rows
    f32x4 sacc[4] = {};
#pragma unroll
    for (int kk = 0; kk < 4; ++kk) {
      int row = wave * 16 + l15;
      s16x8 bk = *(const s16x8*)&Ks[row * 128 + ((kk * 4 + quad) ^ (row & 7)) * 8];
#pragma unroll
      for (int i = 0; i < 4; ++i) sacc[i] = MFMA16(qf[i][kk], bk, sacc[i]);
    }
    // P = maskbit * relu(s) * scale/m  -> bf16 -> LDS (swizzled [q][k])
#pragma unroll
    for (int i = 0; i < 4; ++i)
#pragma unroll
      for (int r = 0; r < 4; ++r) {
        int q = i * 16 + quad * 4 + r;
        int kl = wave * 16 + l15;
        float p = fmaxf(sacc[i][r], 0.f) * invf[i][r];
        p = ((w64 >> q) & 1ull) ? p : 0.f;
        Ps[q * 64 + (((kl >> 3) ^ (q & 7))) * 8 + (kl & 7)] = f2bf(p);
      }
    __syncthreads();  // P ready

    // PV: wave handles c-cols [wave*32, wave*32+32)
#pragma unroll
    for (int ks = 0; ks < 2; ++ks) {
      s16x8 pf[4], vf[2];
#pragma unroll
      for (int i = 0; i < 4; ++i) {
        int row = i * 16 + l15;
        pf[i] = *(const s16x8*)&Ps[row * 64 + ((ks * 4 + quad) ^ (row & 7)) * 8];
      }
#pragma unroll
      for (int j = 0; j < 2; ++j) {
        int row = wave * 32 + j * 16 + l15;
        vf[j] = *(const s16x8*)&Vs[row * 64 + ((ks * 4 + quad) ^ (row & 7)) * 8];
      }
#pragma unroll
      for (int i = 0; i < 4; ++i)
#pragma unroll
        for (int j = 0; j < 2; ++j) pacc[i][j] = MFMA16(pf[i], vf[j], pacc[i][j]);
    }
  }

  // epilogue: CcT[b][q][h*128+c] bf16
  unsigned short* cb = CcT + (size_t)z * S_DIM * U_DIM;
#pragma unroll
  for (int i = 0; i < 4; ++i)
#pragma unroll
    for (int j = 0; j < 2; ++j) {
      f32x4 v = pacc[i][j];
#pragma unroll
      for (int r = 0; r < 4; ++r) {
        int q = q0 + i * 16 + quad * 4 + r;
        int c = h * C_DIM + wave * 32 + j * 16 + l15;
        cb[(size_t)q * U_DIM + c] = f2bf(v[r]);
      }
    }
}

// ---------------------------------------------------------------------------
extern "C" void kernel_launch(void* const* d_in, const int* in_sizes, int n_in,
                              void* d_out, int out_size, void* d_ws, size_t ws_size,
                              hipStream_t stream) {
  const float* x = (const float*)d_in[0];
  const unsigned char* mask_raw = (const unsigned char*)d_in[1];
  const float* w_qkv = (const float*)d_in[2];
  const float* w_out = (const float*)d_in[3];
  float* out = (float*)d_out;

  char* ws = (char*)d_ws;
  int* flag = (int*)ws;                                  // 256 B
  float* invm = (float*)(ws + 256);                      // 64 KB
  unsigned long long* bits = (unsigned long long*)(ws + 256 + 65536);  // 2 MB
  unsigned short* wqkv_bf = (unsigned short*)((char*)bits + (size_t)B_DIM * S_DIM * 16 * 8);
  unsigned short* wout_bf = (unsigned short*)((char*)wqkv_bf + (size_t)3 * U_DIM * U_DIM * 2);
  char* heap = (char*)wout_bf + (size_t)U_DIM * U_DIM * 2;

  const size_t xT_pb = (size_t)U_DIM * S_DIM * 2;
  const size_t qkvT_pb = (size_t)3 * U_DIM * S_DIM * 2;
  const size_t vT_pb = (size_t)U_DIM * S_DIM * 2;
  const size_t ccT_pb = (size_t)U_DIM * S_DIM * 2;
  const size_t per_batch = xT_pb + qkvT_pb + vT_pb + ccT_pb;  // 12.58 MB
  const size_t fixed = (size_t)(heap - ws);
  int nb = (ws_size > fixed) ? (int)((ws_size - fixed) / per_batch) : 1;
  if (nb < 1) nb = 1;
  if (nb > B_DIM) nb = B_DIM;

  unsigned short* xT = (unsigned short*)heap;
  unsigned short* qkvT = (unsigned short*)(heap + (size_t)nb * xT_pb);
  unsigned short* VT = (unsigned short*)(heap + (size_t)nb * (xT_pb + qkvT_pb));
  unsigned short* CcT = (unsigned short*)(heap + (size_t)nb * (xT_pb + qkvT_pb + vT_pb));

  detect_mask<<<1, 256, 0, stream>>>(mask_raw, flag);
  mask_invm<<<(B_DIM * S_DIM) / 4, 256, 0, stream>>>(mask_raw, flag, invm);
  pack_mask<<<dim3(S_DIM / 64, S_DIM / 64, B_DIM), 256, 0, stream>>>(mask_raw, flag, bits);
  cvt_bf16<<<(3 * U_DIM * U_DIM) / 1024, 256, 0, stream>>>(w_qkv, wqkv_bf, 3 * U_DIM * U_DIM);
  cvt_bf16<<<(U_DIM * U_DIM) / 1024, 256, 0, stream>>>(w_out, wout_bf, U_DIM * U_DIM);

  for (int b0 = 0; b0 < B_DIM; b0 += nb) {
    int cnt = (B_DIM - b0 < nb) ? (B_DIM - b0) : nb;
    transpose_x<<<dim3(S_DIM / 32, U_DIM / 32, cnt), 256, 0, stream>>>(
        x + (size_t)b0 * U_DIM * S_DIM, xT);
    gemm_tt<unsigned short><<<dim3(3 * U_DIM / 128, S_DIM / 128, cnt), 256, 0, stream>>>(
        xT, wqkv_bf, qkvT, (long long)U_DIM * S_DIM, 0LL, (long long)3 * U_DIM * S_DIM, 3 * U_DIM);
    transpose_v<<<dim3(S_DIM / 32, U_DIM / 32, cnt), 256, 0, stream>>>(qkvT, VT);
    attn_mfma<<<dim3(S_DIM / 64, H_DIM, cnt), 256, 0, stream>>>(
        qkvT, VT, bits, invm, CcT, b0);
    gemm_tt<float><<<dim3(S_DIM / 128, U_DIM / 128, cnt), 256, 0, stream>>>(
        wout_bf, CcT, out + (size_t)b0 * U_DIM * S_DIM, 0LL,
        (long long)U_DIM * S_DIM, (long long)U_DIM * S_DIM, S_DIM);
  }
}

// Round 6
// 496.664 us; speedup vs baseline: 1.4449x; 1.0265x over previous
//
#include <hip/hip_runtime.h>

#define B_DIM 16
#define U_DIM 1024
#define H_DIM 8
#define S_DIM 1024
#define C_DIM 128
#define KD 1024  // K depth of both projection GEMMs
#define SCALE 0.08838834764831845f  // 1/sqrt(128)

typedef __attribute__((ext_vector_type(8))) short s16x8;
typedef __attribute__((ext_vector_type(4))) float f32x4;

__device__ __forceinline__ void gll16(const void* g, void* l) {
  __builtin_amdgcn_global_load_lds(
      (const __attribute__((address_space(1))) unsigned int*)g,
      (__attribute__((address_space(3))) unsigned int*)l, 16, 0, 0);
}
__device__ __forceinline__ unsigned short f2bf(float f) {
  unsigned u = __float_as_uint(f);
  u += 0x7FFF + ((u >> 16) & 1u);
  return (unsigned short)(u >> 16);
}
#define MFMA16(a, b, c) __builtin_amdgcn_mfma_f32_16x16x32_bf16(a, b, c, 0, 0, 0)

// ---------------------------------------------------------------------------
// Mask storage detection (bool may arrive as u8 / i32 / f32). See R1 notes.
// ---------------------------------------------------------------------------
__global__ void detect_mask(const unsigned char* __restrict__ mask_raw, int* __restrict__ flag) {
  __shared__ int not01, notf;
  if (threadIdx.x == 0) { not01 = 0; notf = 0; }
  __syncthreads();
  const unsigned int* p = (const unsigned int*)mask_raw;
  int l01 = 0, lf = 0;
  for (int i = threadIdx.x; i < 4096; i += 256) {
    unsigned int v = p[i];
    if (v != 0u && v != 1u) l01 = 1;
    if (v != 0u && v != 0x3F800000u) lf = 1;
  }
  if (l01) atomicOr(&not01, 1);
  if (lf) atomicOr(&notf, 1);
  __syncthreads();
  if (threadIdx.x == 0) flag[0] = (!not01) ? 0 : ((!notf) ? 2 : 1);
}

// ---------------------------------------------------------------------------
// Pack mask into k-major bit-words: bits[kt][b][q], word = 64 k bits
// (k = kt*64 + bit). attn reads 16 consecutive u64s per 16 lanes (128B line).
// ---------------------------------------------------------------------------
__global__ __launch_bounds__(256) void pack_mask(const unsigned char* __restrict__ mask_raw,
                                                 const int* __restrict__ flag,
                                                 unsigned long long* __restrict__ bits) {
  __shared__ unsigned char tile[64][80];  // [q][k], pad 80 keeps 16B alignment
  const int t = threadIdx.x;
  const int kt = blockIdx.x * 64, qw = blockIdx.y, b = blockIdx.z;
  const int mk = flag[0];
  const int q = t >> 2, kbase = (t & 3) * 16;
  const size_t row = (size_t)(b * S_DIM + qw * 64 + q);
  if (mk == 1) {
    uint4 v = *(const uint4*)(mask_raw + (row << 10) + kt + kbase);
    *(uint4*)&tile[q][kbase] = v;
  } else if (mk == 0) {
    const int* p = (const int*)mask_raw + (row << 10) + kt + kbase;
#pragma unroll
    for (int j = 0; j < 4; ++j) {
      int4 v = ((const int4*)p)[j];
      uchar4 o;
      o.x = v.x ? 1 : 0; o.y = v.y ? 1 : 0; o.z = v.z ? 1 : 0; o.w = v.w ? 1 : 0;
      *(uchar4*)&tile[q][kbase + j * 4] = o;
    }
  } else {
    const float* p = (const float*)mask_raw + (row << 10) + kt + kbase;
#pragma unroll
    for (int j = 0; j < 4; ++j) {
      float4 v = ((const float4*)p)[j];
      uchar4 o;
      o.x = (v.x != 0.f) ? 1 : 0; o.y = (v.y != 0.f) ? 1 : 0;
      o.z = (v.z != 0.f) ? 1 : 0; o.w = (v.w != 0.f) ? 1 : 0;
      *(uchar4*)&tile[q][kbase + j * 4] = o;
    }
  }
  __syncthreads();
  const int wave = t >> 6, lane = t & 63;
  // ballot along k: word = 64 k-bits at fixed q
#pragma unroll
  for (int qq = 0; qq < 16; ++qq) {
    int qr = wave * 16 + qq;
    unsigned long long bal = __ballot(tile[qr][lane] != 0);
    if (lane == 0)
      bits[(size_t)blockIdx.x * (B_DIM * S_DIM) + (size_t)b * S_DIM + qw * 64 + qr] = bal;
  }
}

// invm from packed bits: rowsum = sum_kt popcount(bits[kt][b][q])
__global__ __launch_bounds__(256) void invm_from_bits(const unsigned long long* __restrict__ bits,
                                                      float* __restrict__ invm) {
  int idx = blockIdx.x * 256 + threadIdx.x;  // = b*S + q
  int s = 0;
#pragma unroll
  for (int kt = 0; kt < S_DIM / 64; ++kt)
    s += __popcll(bits[(size_t)kt * (B_DIM * S_DIM) + idx]);
  invm[idx] = (s > 0) ? (SCALE / (float)s) : 0.f;
}

// fp32 -> bf16 elementwise (weights)
__global__ __launch_bounds__(256) void cvt_bf16(const float* __restrict__ in,
                                                unsigned short* __restrict__ out, int n) {
  int i = (blockIdx.x * 256 + threadIdx.x) * 4;
  if (i < n) {
    float4 v = *(const float4*)(in + i);
    ushort4 o;
    o.x = f2bf(v.x); o.y = f2bf(v.y); o.z = f2bf(v.z); o.w = f2bf(v.w);
    *(ushort4*)(out + i) = o;
  }
}

// x[b][u][s] f32 -> xT[b][s][u] bf16   (32x32 tiles)
__global__ __launch_bounds__(256) void transpose_x(const float* __restrict__ x,
                                                   unsigned short* __restrict__ xT) {
  __shared__ float T[32][33];
  const int t = threadIdx.x, r = t >> 3, c4 = (t & 7) * 4;
  const int s0 = blockIdx.x * 32, u0 = blockIdx.y * 32;
  const size_t base = (size_t)blockIdx.z * U_DIM * S_DIM;
  float4 v = *(const float4*)(x + base + (size_t)(u0 + r) * S_DIM + s0 + c4);
  T[r][c4 + 0] = v.x; T[r][c4 + 1] = v.y; T[r][c4 + 2] = v.z; T[r][c4 + 3] = v.w;
  __syncthreads();
  ushort4 o;
  o.x = f2bf(T[c4 + 0][r]); o.y = f2bf(T[c4 + 1][r]);
  o.z = f2bf(T[c4 + 2][r]); o.w = f2bf(T[c4 + 3][r]);
  *(ushort4*)(xT + base + (size_t)(s0 + r) * U_DIM + u0 + c4) = o;
}

// qkvT[b][k][2048+c] bf16 -> VT[b][c][k] bf16  (32x32 tiles)
__global__ __launch_bounds__(256) void transpose_v(const unsigned short* __restrict__ qkvT,
                                                   unsigned short* __restrict__ VT) {
  __shared__ unsigned short T[32][34];
  const int t = threadIdx.x, r = t >> 3, c4 = (t & 7) * 4;
  const int k0 = blockIdx.x * 32, c0 = blockIdx.y * 32;
  const unsigned short* qb = qkvT + (size_t)blockIdx.z * S_DIM * (3 * U_DIM);
  ushort4 v = *(const ushort4*)(qb + (size_t)(k0 + r) * (3 * U_DIM) + 2 * U_DIM + c0 + c4);
  T[r][c4 + 0] = v.x; T[r][c4 + 1] = v.y; T[r][c4 + 2] = v.z; T[r][c4 + 3] = v.w;
  __syncthreads();
  ushort4 o;
  o.x = T[c4 + 0][r]; o.y = T[c4 + 1][r]; o.z = T[c4 + 2][r]; o.w = T[c4 + 3][r];
  *(ushort4*)(VT + (size_t)blockIdx.z * U_DIM * S_DIM + (size_t)(c0 + r) * S_DIM + k0 + c4) = o;
}

// ---------------------------------------------------------------------------
// bf16 MFMA GEMM (m97 structure + XOR-swizzled LDS chunks):
//   D[m][n] = sum_k A[m][k] * B[n][k];  A,B row-major with K=1024 contiguous.
// ---------------------------------------------------------------------------
template <typename OUT>
__global__ __launch_bounds__(256) void gemm_tt(const unsigned short* __restrict__ A,
                                               const unsigned short* __restrict__ Bm,
                                               OUT* __restrict__ D,
                                               long long sAb, long long sBb, long long sDb,
                                               int N) {
  __shared__ unsigned short sA[128 * 32];
  __shared__ unsigned short sB[128 * 32];
  const int tid = threadIdx.x, wave = tid >> 6, lane = tid & 63;
  const int l15 = lane & 15, quad = lane >> 4;
  const int m0 = blockIdx.y * 128, n0 = blockIdx.x * 128;
  A += (size_t)blockIdx.z * sAb;
  Bm += (size_t)blockIdx.z * sBb;
  D += (size_t)blockIdx.z * sDb;
  const int wm = (wave >> 1) * 64, wn = (wave & 1) * 64;
  f32x4 acc[4][4] = {};

  for (int k0 = 0; k0 < KD; k0 += 32) {
#pragma unroll
    for (int t = 0; t < 2; ++t) {
      int p = wave * 128 + t * 64 + lane;
      int row = p >> 2, kc = (p & 3) ^ (row & 3);
      gll16(A + (size_t)(m0 + row) * KD + k0 + kc * 8, &sA[(wave * 128 + t * 64) * 8]);
    }
#pragma unroll
    for (int t = 0; t < 2; ++t) {
      int p = wave * 128 + t * 64 + lane;
      int row = p >> 2, kc = (p & 3) ^ (row & 3);
      gll16(Bm + (size_t)(n0 + row) * KD + k0 + kc * 8, &sB[(wave * 128 + t * 64) * 8]);
    }
    __syncthreads();
    s16x8 af[4], bf[4];
#pragma unroll
    for (int i = 0; i < 4; ++i) {
      int row = wm + i * 16 + l15;
      af[i] = *(const s16x8*)&sA[row * 32 + (quad ^ (row & 3)) * 8];
    }
#pragma unroll
    for (int j = 0; j < 4; ++j) {
      int row = wn + j * 16 + l15;
      bf[j] = *(const s16x8*)&sB[row * 32 + (quad ^ (row & 3)) * 8];
    }
#pragma unroll
    for (int i = 0; i < 4; ++i)
#pragma unroll
      for (int j = 0; j < 4; ++j) acc[i][j] = MFMA16(af[i], bf[j], acc[i][j]);
    __syncthreads();
  }
#pragma unroll
  for (int i = 0; i < 4; ++i)
#pragma unroll
    for (int j = 0; j < 4; ++j) {
      f32x4 v = acc[i][j];
#pragma unroll
      for (int r = 0; r < 4; ++r) {
        int m = m0 + wm + i * 16 + quad * 4 + r;
        int n = n0 + wn + j * 16 + l15;
        if constexpr (sizeof(OUT) == 2) D[(size_t)m * N + n] = f2bf(v[r]);
        else D[(size_t)m * N + n] = v[r];
      }
    }
}

// ---------------------------------------------------------------------------
// Fused masked-relu attention. Scores computed as D[k][q] (K rows = MFMA m,
// Q cols = MFMA n): each thread then holds 4 CONSECUTIVE k per q, so the
// P->LDS pass is 4x ds_write_b64 instead of 16 scalar b16 writes, and invm
// is 1 scalar per (thread,j). Occ 2 (L2-friendly; occ 3 thrashed, R3/R4).
// ---------------------------------------------------------------------------
__global__ __launch_bounds__(256, 2) void attn_mfma(const unsigned short* __restrict__ qkvT,
                                                    const unsigned short* __restrict__ VT,
                                                    const unsigned long long* __restrict__ bits,
                                                    const float* __restrict__ invm,
                                                    unsigned short* __restrict__ CcT, int b0) {
  __shared__ unsigned short Qs[64 * 128];  // [q][c] swizzled (16 KB)
  __shared__ unsigned short Ks[64 * 128];  // [k][c] swizzled (16 KB)
  __shared__ unsigned short Vs[128 * 64];  // [c][k] swizzled (16 KB)
  __shared__ unsigned short Ps[64 * 64];   // [q][k] swizzled (8 KB)
  __shared__ float invs[64];

  const int tid = threadIdx.x, wave = tid >> 6, lane = tid & 63;
  const int l15 = lane & 15, quad = lane >> 4;
  const int qt = blockIdx.x, h = blockIdx.y, z = blockIdx.z;
  const int q0 = qt * 64, b = b0 + z;
  const unsigned short* qB = qkvT + (size_t)z * S_DIM * (3 * U_DIM);
  const unsigned short* Vb = VT + (size_t)z * U_DIM * S_DIM + (size_t)h * C_DIM * S_DIM;

  // stage Q tile (64 rows x 16 chunks, chunk ^= row&7)
#pragma unroll
  for (int t = 0; t < 4; ++t) {
    int p = wave * 256 + t * 64 + lane;
    int row = p >> 4, c = (p & 15) ^ (row & 7);
    gll16(qB + (size_t)(q0 + row) * (3 * U_DIM) + h * C_DIM + c * 8,
          &Qs[(wave * 256 + t * 64) * 8]);
  }
  if (tid < 64) invs[tid] = invm[(size_t)b * S_DIM + q0 + tid];
  __syncthreads();

  // Q fragments (B-operand: rows j*16+l15) + invm scalars to registers
  s16x8 qf[4][4];
#pragma unroll
  for (int j = 0; j < 4; ++j)
#pragma unroll
    for (int kk = 0; kk < 4; ++kk) {
      int row = j * 16 + l15;
      qf[j][kk] = *(const s16x8*)&Qs[row * 128 + ((kk * 4 + quad) ^ (row & 7)) * 8];
    }
  float invf[4];
#pragma unroll
  for (int j = 0; j < 4; ++j) invf[j] = invs[j * 16 + l15];

  f32x4 pacc[4][2] = {};

  for (int kt = 0; kt < S_DIM / 64; ++kt) {
    const int k0t = kt * 64;
    __syncthreads();  // prev PV done (Ks/Vs free)
    // stage K tile
#pragma unroll
    for (int t = 0; t < 4; ++t) {
      int p = wave * 256 + t * 64 + lane;
      int row = p >> 4, c = (p & 15) ^ (row & 7);
      gll16(qB + (size_t)(k0t + row) * (3 * U_DIM) + U_DIM + h * C_DIM + c * 8,
            &Ks[(wave * 256 + t * 64) * 8]);
    }
    // stage V tile ([c][k], 128 rows x 8 chunks)
#pragma unroll
    for (int t = 0; t < 4; ++t) {
      int p = wave * 256 + t * 64 + lane;
      int row = p >> 3, kc = (p & 7) ^ (row & 7);
      gll16(Vb + (size_t)row * S_DIM + k0t + kc * 8, &Vs[(wave * 256 + t * 64) * 8]);
    }
    // mask words: 64 k-bits at q = q0 + j*16 + l15 (coalesced 128B per j)
    unsigned long long w64[4];
    {
      const unsigned long long* mw =
          bits + (size_t)kt * (B_DIM * S_DIM) + (size_t)b * S_DIM + q0;
#pragma unroll
      for (int j = 0; j < 4; ++j) w64[j] = mw[j * 16 + l15];
    }
    __syncthreads();  // K/V tiles ready

    // scores D[k][q]: wave handles k rows [wave*16, wave*16+16), all 64 q
    s16x8 af[4];
#pragma unroll
    for (int kk = 0; kk < 4; ++kk) {
      int row = wave * 16 + l15;
      af[kk] = *(const s16x8*)&Ks[row * 128 + ((kk * 4 + quad) ^ (row & 7)) * 8];
    }
    f32x4 sacc[4] = {};
#pragma unroll
    for (int kk = 0; kk < 4; ++kk)
#pragma unroll
      for (int j = 0; j < 4; ++j) sacc[j] = MFMA16(af[kk], qf[j][kk], sacc[j]);

    // P = maskbit * relu(s) * scale/m -> bf16x4 (4 consecutive k) -> LDS b64
#pragma unroll
    for (int j = 0; j < 4; ++j) {
      unsigned int pk[2];
#pragma unroll
      for (int half = 0; half < 2; ++half) {
        unsigned int w = 0;
#pragma unroll
        for (int r2 = 0; r2 < 2; ++r2) {
          int r = half * 2 + r2;
          float p = fmaxf(sacc[j][r], 0.f) * invf[j];
          p = ((w64[j] >> (wave * 16 + quad * 4 + r)) & 1ull) ? p : 0.f;
          w |= (unsigned int)f2bf(p) << (r2 * 16);
        }
        pk[half] = w;
      }
      int q = j * 16 + l15;
      int chunk = (wave * 2 + (quad >> 1)) ^ (q & 7);
      *(uint2*)&Ps[q * 64 + chunk * 8 + (quad & 1) * 4] = make_uint2(pk[0], pk[1]);
    }
    __syncthreads();  // P ready

    // PV: wave handles c-cols [wave*32, wave*32+32)
#pragma unroll
    for (int ks = 0; ks < 2; ++ks) {
      s16x8 pf[4], vf[2];
#pragma unroll
      for (int i = 0; i < 4; ++i) {
        int row = i * 16 + l15;
        pf[i] = *(const s16x8*)&Ps[row * 64 + ((ks * 4 + quad) ^ (row & 7)) * 8];
      }
#pragma unroll
      for (int j = 0; j < 2; ++j) {
        int row = wave * 32 + j * 16 + l15;
        vf[j] = *(const s16x8*)&Vs[row * 64 + ((ks * 4 + quad) ^ (row & 7)) * 8];
      }
#pragma unroll
      for (int i = 0; i < 4; ++i)
#pragma unroll
        for (int j = 0; j < 2; ++j) pacc[i][j] = MFMA16(pf[i], vf[j], pacc[i][j]);
    }
  }

  // epilogue: CcT[b][q][h*128+c] bf16
  unsigned short* cb = CcT + (size_t)z * S_DIM * U_DIM;
#pragma unroll
  for (int i = 0; i < 4; ++i)
#pragma unroll
    for (int j = 0; j < 2; ++j) {
      f32x4 v = pacc[i][j];
#pragma unroll
      for (int r = 0; r < 4; ++r) {
        int q = q0 + i * 16 + quad * 4 + r;
        int c = h * C_DIM + wave * 32 + j * 16 + l15;
        cb[(size_t)q * U_DIM + c] = f2bf(v[r]);
      }
    }
}

// ---------------------------------------------------------------------------
extern "C" void kernel_launch(void* const* d_in, const int* in_sizes, int n_in,
                              void* d_out, int out_size, void* d_ws, size_t ws_size,
                              hipStream_t stream) {
  const float* x = (const float*)d_in[0];
  const unsigned char* mask_raw = (const unsigned char*)d_in[1];
  const float* w_qkv = (const float*)d_in[2];
  const float* w_out = (const float*)d_in[3];
  float* out = (float*)d_out;

  char* ws = (char*)d_ws;
  int* flag = (int*)ws;                                  // 256 B
  float* invm = (float*)(ws + 256);                      // 64 KB
  unsigned long long* bits = (unsigned long long*)(ws + 256 + 65536);  // 2 MB
  unsigned short* wqkv_bf = (unsigned short*)((char*)bits + (size_t)B_DIM * S_DIM * 16 * 8);
  unsigned short* wout_bf = (unsigned short*)((char*)wqkv_bf + (size_t)3 * U_DIM * U_DIM * 2);
  char* heap = (char*)wout_bf + (size_t)U_DIM * U_DIM * 2;

  const size_t xT_pb = (size_t)U_DIM * S_DIM * 2;
  const size_t qkvT_pb = (size_t)3 * U_DIM * S_DIM * 2;
  const size_t vT_pb = (size_t)U_DIM * S_DIM * 2;
  const size_t ccT_pb = (size_t)U_DIM * S_DIM * 2;
  const size_t per_batch = xT_pb + qkvT_pb + vT_pb + ccT_pb;  // 12.58 MB
  const size_t fixed = (size_t)(heap - ws);
  int nb = (ws_size > fixed) ? (int)((ws_size - fixed) / per_batch) : 1;
  if (nb < 1) nb = 1;
  if (nb > B_DIM) nb = B_DIM;

  unsigned short* xT = (unsigned short*)heap;
  unsigned short* qkvT = (unsigned short*)(heap + (size_t)nb * xT_pb);
  unsigned short* VT = (unsigned short*)(heap + (size_t)nb * (xT_pb + qkvT_pb));
  unsigned short* CcT = (unsigned short*)(heap + (size_t)nb * (xT_pb + qkvT_pb + vT_pb));

  detect_mask<<<1, 256, 0, stream>>>(mask_raw, flag);
  pack_mask<<<dim3(S_DIM / 64, S_DIM / 64, B_DIM), 256, 0, stream>>>(mask_raw, flag, bits);
  invm_from_bits<<<(B_DIM * S_DIM) / 256, 256, 0, stream>>>(bits, invm);
  cvt_bf16<<<(3 * U_DIM * U_DIM) / 1024, 256, 0, stream>>>(w_qkv, wqkv_bf, 3 * U_DIM * U_DIM);
  cvt_bf16<<<(U_DIM * U_DIM) / 1024, 256, 0, stream>>>(w_out, wout_bf, U_DIM * U_DIM);

  for (int b0 = 0; b0 < B_DIM; b0 += nb) {
    int cnt = (B_DIM - b0 < nb) ? (B_DIM - b0) : nb;
    transpose_x<<<dim3(S_DIM / 32, U_DIM / 32, cnt), 256, 0, stream>>>(
        x + (size_t)b0 * U_DIM * S_DIM, xT);
    gemm_tt<unsigned short><<<dim3(3 * U_DIM / 128, S_DIM / 128, cnt), 256, 0, stream>>>(
        xT, wqkv_bf, qkvT, (long long)U_DIM * S_DIM, 0LL, (long long)3 * U_DIM * S_DIM, 3 * U_DIM);
    transpose_v<<<dim3(S_DIM / 32, U_DIM / 32, cnt), 256, 0, stream>>>(qkvT, VT);
    attn_mfma<<<dim3(S_DIM / 64, H_DIM, cnt), 256, 0, stream>>>(
        qkvT, VT, bits, invm, CcT, b0);
    gemm_tt<float><<<dim3(S_DIM / 128, U_DIM / 128, cnt), 256, 0, stream>>>(
        wout_bf, CcT, out + (size_t)b0 * U_DIM * S_DIM, 0LL,
        (long long)U_DIM * S_DIM, (long long)U_DIM * S_DIM, S_DIM);
  }
}

// Round 7
// 495.461 us; speedup vs baseline: 1.4484x; 1.0024x over previous
//
#include <hip/hip_runtime.h>

#define B_DIM 16
#define U_DIM 1024
#define H_DIM 8
#define S_DIM 1024
#define C_DIM 128
#define KD 1024  // K depth of both projection GEMMs
#define SCALE 0.08838834764831845f  // 1/sqrt(128)

typedef __attribute__((ext_vector_type(8))) short s16x8;
typedef __attribute__((ext_vector_type(4))) float f32x4;

__device__ __forceinline__ void gll16(const void* g, void* l) {
  __builtin_amdgcn_global_load_lds(
      (const __attribute__((address_space(1))) unsigned int*)g,
      (__attribute__((address_space(3))) unsigned int*)l, 16, 0, 0);
}
__device__ __forceinline__ unsigned short f2bf(float f) {
  unsigned u = __float_as_uint(f);
  u += 0x7FFF + ((u >> 16) & 1u);
  return (unsigned short)(u >> 16);
}
#define MFMA16(a, b, c) __builtin_amdgcn_mfma_f32_16x16x32_bf16(a, b, c, 0, 0, 0)

// ---------------------------------------------------------------------------
// Mask storage detection (bool may arrive as u8 / i32 / f32). See R1 notes.
// ---------------------------------------------------------------------------
__global__ void detect_mask(const unsigned char* __restrict__ mask_raw, int* __restrict__ flag) {
  __shared__ int not01, notf;
  if (threadIdx.x == 0) { not01 = 0; notf = 0; }
  __syncthreads();
  const unsigned int* p = (const unsigned int*)mask_raw;
  int l01 = 0, lf = 0;
  for (int i = threadIdx.x; i < 4096; i += 256) {
    unsigned int v = p[i];
    if (v != 0u && v != 1u) l01 = 1;
    if (v != 0u && v != 0x3F800000u) lf = 1;
  }
  if (l01) atomicOr(&not01, 1);
  if (lf) atomicOr(&notf, 1);
  __syncthreads();
  if (threadIdx.x == 0) flag[0] = (!not01) ? 0 : ((!notf) ? 2 : 1);
}

// ---------------------------------------------------------------------------
// Pack mask into k-major bit-words: bits[kt][b][q], word = 64 k bits
// (k = kt*64 + bit). attn reads 16 consecutive u64s per 16 lanes (128B line).
// ---------------------------------------------------------------------------
__global__ __launch_bounds__(256) void pack_mask(const unsigned char* __restrict__ mask_raw,
                                                 const int* __restrict__ flag,
                                                 unsigned long long* __restrict__ bits) {
  __shared__ unsigned char tile[64][80];  // [q][k], pad 80 keeps 16B alignment
  const int t = threadIdx.x;
  const int kt = blockIdx.x * 64, qw = blockIdx.y, b = blockIdx.z;
  const int mk = flag[0];
  const int q = t >> 2, kbase = (t & 3) * 16;
  const size_t row = (size_t)(b * S_DIM + qw * 64 + q);
  if (mk == 1) {
    uint4 v = *(const uint4*)(mask_raw + (row << 10) + kt + kbase);
    *(uint4*)&tile[q][kbase] = v;
  } else if (mk == 0) {
    const int* p = (const int*)mask_raw + (row << 10) + kt + kbase;
#pragma unroll
    for (int j = 0; j < 4; ++j) {
      int4 v = ((const int4*)p)[j];
      uchar4 o;
      o.x = v.x ? 1 : 0; o.y = v.y ? 1 : 0; o.z = v.z ? 1 : 0; o.w = v.w ? 1 : 0;
      *(uchar4*)&tile[q][kbase + j * 4] = o;
    }
  } else {
    const float* p = (const float*)mask_raw + (row << 10) + kt + kbase;
#pragma unroll
    for (int j = 0; j < 4; ++j) {
      float4 v = ((const float4*)p)[j];
      uchar4 o;
      o.x = (v.x != 0.f) ? 1 : 0; o.y = (v.y != 0.f) ? 1 : 0;
      o.z = (v.z != 0.f) ? 1 : 0; o.w = (v.w != 0.f) ? 1 : 0;
      *(uchar4*)&tile[q][kbase + j * 4] = o;
    }
  }
  __syncthreads();
  const int wave = t >> 6, lane = t & 63;
  // ballot along k: word = 64 k-bits at fixed q
#pragma unroll
  for (int qq = 0; qq < 16; ++qq) {
    int qr = wave * 16 + qq;
    unsigned long long bal = __ballot(tile[qr][lane] != 0);
    if (lane == 0)
      bits[(size_t)blockIdx.x * (B_DIM * S_DIM) + (size_t)b * S_DIM + qw * 64 + qr] = bal;
  }
}

// invm from packed bits: rowsum = sum_kt popcount(bits[kt][b][q])
__global__ __launch_bounds__(256) void invm_from_bits(const unsigned long long* __restrict__ bits,
                                                      float* __restrict__ invm) {
  int idx = blockIdx.x * 256 + threadIdx.x;  // = b*S + q
  int s = 0;
#pragma unroll
  for (int kt = 0; kt < S_DIM / 64; ++kt)
    s += __popcll(bits[(size_t)kt * (B_DIM * S_DIM) + idx]);
  invm[idx] = (s > 0) ? (SCALE / (float)s) : 0.f;
}

// fp32 -> bf16 elementwise (weights)
__global__ __launch_bounds__(256) void cvt_bf16(const float* __restrict__ in,
                                                unsigned short* __restrict__ out, int n) {
  int i = (blockIdx.x * 256 + threadIdx.x) * 4;
  if (i < n) {
    float4 v = *(const float4*)(in + i);
    ushort4 o;
    o.x = f2bf(v.x); o.y = f2bf(v.y); o.z = f2bf(v.z); o.w = f2bf(v.w);
    *(ushort4*)(out + i) = o;
  }
}

// x[b][u][s] f32 -> xT[b][s][u] bf16   (32x32 tiles)
__global__ __launch_bounds__(256) void transpose_x(const float* __restrict__ x,
                                                   unsigned short* __restrict__ xT) {
  __shared__ float T[32][33];
  const int t = threadIdx.x, r = t >> 3, c4 = (t & 7) * 4;
  const int s0 = blockIdx.x * 32, u0 = blockIdx.y * 32;
  const size_t base = (size_t)blockIdx.z * U_DIM * S_DIM;
  float4 v = *(const float4*)(x + base + (size_t)(u0 + r) * S_DIM + s0 + c4);
  T[r][c4 + 0] = v.x; T[r][c4 + 1] = v.y; T[r][c4 + 2] = v.z; T[r][c4 + 3] = v.w;
  __syncthreads();
  ushort4 o;
  o.x = f2bf(T[c4 + 0][r]); o.y = f2bf(T[c4 + 1][r]);
  o.z = f2bf(T[c4 + 2][r]); o.w = f2bf(T[c4 + 3][r]);
  *(ushort4*)(xT + base + (size_t)(s0 + r) * U_DIM + u0 + c4) = o;
}

// qkvT[b][k][2048+c] bf16 -> VT[b][c][k] bf16  (32x32 tiles)
__global__ __launch_bounds__(256) void transpose_v(const unsigned short* __restrict__ qkvT,
                                                   unsigned short* __restrict__ VT) {
  __shared__ unsigned short T[32][34];
  const int t = threadIdx.x, r = t >> 3, c4 = (t & 7) * 4;
  const int k0 = blockIdx.x * 32, c0 = blockIdx.y * 32;
  const unsigned short* qb = qkvT + (size_t)blockIdx.z * S_DIM * (3 * U_DIM);
  ushort4 v = *(const ushort4*)(qb + (size_t)(k0 + r) * (3 * U_DIM) + 2 * U_DIM + c0 + c4);
  T[r][c4 + 0] = v.x; T[r][c4 + 1] = v.y; T[r][c4 + 2] = v.z; T[r][c4 + 3] = v.w;
  __syncthreads();
  ushort4 o;
  o.x = T[c4 + 0][r]; o.y = T[c4 + 1][r]; o.z = T[c4 + 2][r]; o.w = T[c4 + 3][r];
  *(ushort4*)(VT + (size_t)blockIdx.z * U_DIM * S_DIM + (size_t)(c0 + r) * S_DIM + k0 + c4) = o;
}

// ---------------------------------------------------------------------------
// bf16 MFMA GEMM, BK=64 (32 KB LDS): halved barrier count vs BK=32, 32 MFMA
// per staging barrier (AITER-like cadence). XOR-swizzled 16B chunks.
//   D[m][n] = sum_k A[m][k] * B[n][k];  A,B row-major with K=1024 contiguous.
// ---------------------------------------------------------------------------
template <typename OUT>
__global__ __launch_bounds__(256) void gemm_tt(const unsigned short* __restrict__ A,
                                               const unsigned short* __restrict__ Bm,
                                               OUT* __restrict__ D,
                                               long long sAb, long long sBb, long long sDb,
                                               int N) {
  __shared__ unsigned short sA[128 * 64];
  __shared__ unsigned short sB[128 * 64];
  const int tid = threadIdx.x, wave = tid >> 6, lane = tid & 63;
  const int l15 = lane & 15, quad = lane >> 4;
  const int m0 = blockIdx.y * 128, n0 = blockIdx.x * 128;
  A += (size_t)blockIdx.z * sAb;
  Bm += (size_t)blockIdx.z * sBb;
  D += (size_t)blockIdx.z * sDb;
  const int wm = (wave >> 1) * 64, wn = (wave & 1) * 64;
  f32x4 acc[4][4] = {};

  for (int k0 = 0; k0 < KD; k0 += 64) {
#pragma unroll
    for (int t = 0; t < 4; ++t) {
      int p = wave * 256 + t * 64 + lane;
      int row = p >> 3, kc = (p & 7) ^ (row & 7);
      gll16(A + (size_t)(m0 + row) * KD + k0 + kc * 8, &sA[(wave * 256 + t * 64) * 8]);
    }
#pragma unroll
    for (int t = 0; t < 4; ++t) {
      int p = wave * 256 + t * 64 + lane;
      int row = p >> 3, kc = (p & 7) ^ (row & 7);
      gll16(Bm + (size_t)(n0 + row) * KD + k0 + kc * 8, &sB[(wave * 256 + t * 64) * 8]);
    }
    __syncthreads();
#pragma unroll
    for (int kk = 0; kk < 2; ++kk) {
      s16x8 af[4], bf[4];
#pragma unroll
      for (int i = 0; i < 4; ++i) {
        int row = wm + i * 16 + l15;
        af[i] = *(const s16x8*)&sA[row * 64 + ((kk * 4 + quad) ^ (row & 7)) * 8];
      }
#pragma unroll
      for (int j = 0; j < 4; ++j) {
        int row = wn + j * 16 + l15;
        bf[j] = *(const s16x8*)&sB[row * 64 + ((kk * 4 + quad) ^ (row & 7)) * 8];
      }
#pragma unroll
      for (int i = 0; i < 4; ++i)
#pragma unroll
        for (int j = 0; j < 4; ++j) acc[i][j] = MFMA16(af[i], bf[j], acc[i][j]);
    }
    __syncthreads();
  }
#pragma unroll
  for (int i = 0; i < 4; ++i)
#pragma unroll
    for (int j = 0; j < 4; ++j) {
      f32x4 v = acc[i][j];
#pragma unroll
      for (int r = 0; r < 4; ++r) {
        int m = m0 + wm + i * 16 + quad * 4 + r;
        int n = n0 + wn + j * 16 + l15;
        if constexpr (sizeof(OUT) == 2) D[(size_t)m * N + n] = f2bf(v[r]);
        else D[(size_t)m * N + n] = v[r];
      }
    }
}

// ---------------------------------------------------------------------------
// Fused masked-relu attention, 2-barrier pipelined K-loop.
// Dead Q staging buffer doubles as V ping-pong; K(t+1)/V(t+1) staging issued
// after the P-ready barrier so it overlaps PV compute. Occ 2 (L2-friendly).
// ---------------------------------------------------------------------------
__global__ __launch_bounds__(256, 2) void attn_mfma(const unsigned short* __restrict__ qkvT,
                                                    const unsigned short* __restrict__ VT,
                                                    const unsigned long long* __restrict__ bits,
                                                    const float* __restrict__ invm,
                                                    unsigned short* __restrict__ CcT, int b0) {
  __shared__ unsigned short QV[64 * 128];  // Q staging, then V ping buf (16 KB)
  __shared__ unsigned short Ks[64 * 128];  // [k][c] swizzled (16 KB)
  __shared__ unsigned short Vs[128 * 64];  // [c][k] swizzled (16 KB)
  __shared__ unsigned short Ps[64 * 64];   // [q][k] swizzled (8 KB)
  __shared__ float invs[64];

  const int tid = threadIdx.x, wave = tid >> 6, lane = tid & 63;
  const int l15 = lane & 15, quad = lane >> 4;
  const int qt = blockIdx.x, h = blockIdx.y, z = blockIdx.z;
  const int q0 = qt * 64, b = b0 + z;
  const unsigned short* qB = qkvT + (size_t)z * S_DIM * (3 * U_DIM);
  const unsigned short* Vb = VT + (size_t)z * U_DIM * S_DIM + (size_t)h * C_DIM * S_DIM;

  // prologue: stage Q -> QV, K(0) -> Ks, V(0) -> Vs
#pragma unroll
  for (int t = 0; t < 4; ++t) {
    int p = wave * 256 + t * 64 + lane;
    int row = p >> 4, c = (p & 15) ^ (row & 7);
    gll16(qB + (size_t)(q0 + row) * (3 * U_DIM) + h * C_DIM + c * 8,
          &QV[(wave * 256 + t * 64) * 8]);
    gll16(qB + (size_t)(row) * (3 * U_DIM) + U_DIM + h * C_DIM + c * 8,
          &Ks[(wave * 256 + t * 64) * 8]);
    int vrow = p >> 3, vkc = (p & 7) ^ (vrow & 7);
    gll16(Vb + (size_t)vrow * S_DIM + vkc * 8, &Vs[(wave * 256 + t * 64) * 8]);
  }
  if (tid < 64) invs[tid] = invm[(size_t)b * S_DIM + q0 + tid];
  __syncthreads();

  // Q fragments (B-operand: rows j*16+l15) + invm scalars to registers.
  // QV is dead after this point for all waves by the first P-ready barrier.
  s16x8 qf[4][4];
#pragma unroll
  for (int j = 0; j < 4; ++j)
#pragma unroll
    for (int kk = 0; kk < 4; ++kk) {
      int row = j * 16 + l15;
      qf[j][kk] = *(const s16x8*)&QV[row * 128 + ((kk * 4 + quad) ^ (row & 7)) * 8];
    }
  float invf[4];
#pragma unroll
  for (int j = 0; j < 4; ++j) invf[j] = invs[j * 16 + l15];

  f32x4 pacc[4][2] = {};

  for (int kt = 0; kt < S_DIM / 64; ++kt) {
    // mask words: 64 k-bits at q = q0 + j*16 + l15 (coalesced 128B per j)
    unsigned long long w64[4];
    {
      const unsigned long long* mw =
          bits + (size_t)kt * (B_DIM * S_DIM) + (size_t)b * S_DIM + q0;
#pragma unroll
      for (int j = 0; j < 4; ++j) w64[j] = mw[j * 16 + l15];
    }

    // scores D[k][q]: wave handles k rows [wave*16, wave*16+16), all 64 q
    s16x8 af[4];
#pragma unroll
    for (int kk = 0; kk < 4; ++kk) {
      int row = wave * 16 + l15;
      af[kk] = *(const s16x8*)&Ks[row * 128 + ((kk * 4 + quad) ^ (row & 7)) * 8];
    }
    f32x4 sacc[4] = {};
#pragma unroll
    for (int kk = 0; kk < 4; ++kk)
#pragma unroll
      for (int j = 0; j < 4; ++j) sacc[j] = MFMA16(af[kk], qf[j][kk], sacc[j]);

    // P = maskbit * relu(s) * scale/m -> bf16x4 (4 consecutive k) -> LDS b64
#pragma unroll
    for (int j = 0; j < 4; ++j) {
      unsigned int pk[2];
#pragma unroll
      for (int half = 0; half < 2; ++half) {
        unsigned int w = 0;
#pragma unroll
        for (int r2 = 0; r2 < 2; ++r2) {
          int r = half * 2 + r2;
          float p = fmaxf(sacc[j][r], 0.f) * invf[j];
          p = ((w64[j] >> (wave * 16 + quad * 4 + r)) & 1ull) ? p : 0.f;
          w |= (unsigned int)f2bf(p) << (r2 * 16);
        }
        pk[half] = w;
      }
      int q = j * 16 + l15;
      int chunk = (wave * 2 + (quad >> 1)) ^ (q & 7);
      *(uint2*)&Ps[q * 64 + chunk * 8 + (quad & 1) * 4] = make_uint2(pk[0], pk[1]);
    }
    __syncthreads();  // P ready; all waves done reading Ks (and QV on kt==0)

    // overlap: stage K(t+1)->Ks, V(t+1)->other buf while PV computes
    if (kt < S_DIM / 64 - 1) {
      const int kn = (kt + 1) * 64;
      unsigned short* vdst = (kt & 1) ? Vs : QV;
#pragma unroll
      for (int t = 0; t < 4; ++t) {
        int p = wave * 256 + t * 64 + lane;
        int row = p >> 4, c = (p & 15) ^ (row & 7);
        gll16(qB + (size_t)(kn + row) * (3 * U_DIM) + U_DIM + h * C_DIM + c * 8,
              &Ks[(wave * 256 + t * 64) * 8]);
        int vrow = p >> 3, vkc = (p & 7) ^ (vrow & 7);
        gll16(Vb + (size_t)vrow * S_DIM + kn + vkc * 8, &vdst[(wave * 256 + t * 64) * 8]);
      }
    }

    // PV from V(kt) (even -> Vs, odd -> QV): wave c-cols [wave*32, +32)
    const unsigned short* vbuf = (kt & 1) ? QV : Vs;
#pragma unroll
    for (int ks = 0; ks < 2; ++ks) {
      s16x8 pf[4], vf[2];
#pragma unroll
      for (int i = 0; i < 4; ++i) {
        int row = i * 16 + l15;
        pf[i] = *(const s16x8*)&Ps[row * 64 + ((ks * 4 + quad) ^ (row & 7)) * 8];
      }
#pragma unroll
      for (int j = 0; j < 2; ++j) {
        int row = wave * 32 + j * 16 + l15;
        vf[j] = *(const s16x8*)&vbuf[row * 64 + ((ks * 4 + quad) ^ (row & 7)) * 8];
      }
#pragma unroll
      for (int i = 0; i < 4; ++i)
#pragma unroll
        for (int j = 0; j < 2; ++j) pacc[i][j] = MFMA16(pf[i], vf[j], pacc[i][j]);
    }
    __syncthreads();  // PV done + staging drained (vmcnt(0) at barrier)
  }

  // epilogue: CcT[b][q][h*128+c] bf16
  unsigned short* cb = CcT + (size_t)z * S_DIM * U_DIM;
#pragma unroll
  for (int i = 0; i < 4; ++i)
#pragma unroll
    for (int j = 0; j < 2; ++j) {
      f32x4 v = pacc[i][j];
#pragma unroll
      for (int r = 0; r < 4; ++r) {
        int q = q0 + i * 16 + quad * 4 + r;
        int c = h * C_DIM + wave * 32 + j * 16 + l15;
        cb[(size_t)q * U_DIM + c] = f2bf(v[r]);
      }
    }
}

// ---------------------------------------------------------------------------
extern "C" void kernel_launch(void* const* d_in, const int* in_sizes, int n_in,
                              void* d_out, int out_size, void* d_ws, size_t ws_size,
                              hipStream_t stream) {
  const float* x = (const float*)d_in[0];
  const unsigned char* mask_raw = (const unsigned char*)d_in[1];
  const float* w_qkv = (const float*)d_in[2];
  const float* w_out = (const float*)d_in[3];
  float* out = (float*)d_out;

  char* ws = (char*)d_ws;
  int* flag = (int*)ws;                                  // 256 B
  float* invm = (float*)(ws + 256);                      // 64 KB
  unsigned long long* bits = (unsigned long long*)(ws + 256 + 65536);  // 2 MB
  unsigned short* wqkv_bf = (unsigned short*)((char*)bits + (size_t)B_DIM * S_DIM * 16 * 8);
  unsigned short* wout_bf = (unsigned short*)((char*)wqkv_bf + (size_t)3 * U_DIM * U_DIM * 2);
  char* heap = (char*)wout_bf + (size_t)U_DIM * U_DIM * 2;

  const size_t xT_pb = (size_t)U_DIM * S_DIM * 2;
  const size_t qkvT_pb = (size_t)3 * U_DIM * S_DIM * 2;
  const size_t vT_pb = (size_t)U_DIM * S_DIM * 2;
  const size_t ccT_pb = (size_t)U_DIM * S_DIM * 2;
  const size_t per_batch = xT_pb + qkvT_pb + vT_pb + ccT_pb;  // 12.58 MB
  const size_t fixed = (size_t)(heap - ws);
  int nb = (ws_size > fixed) ? (int)((ws_size - fixed) / per_batch) : 1;
  if (nb < 1) nb = 1;
  if (nb > B_DIM) nb = B_DIM;

  unsigned short* xT = (unsigned short*)heap;
  unsigned short* qkvT = (unsigned short*)(heap + (size_t)nb * xT_pb);
  unsigned short* VT = (unsigned short*)(heap + (size_t)nb * (xT_pb + qkvT_pb));
  unsigned short* CcT = (unsigned short*)(heap + (size_t)nb * (xT_pb + qkvT_pb + vT_pb));

  detect_mask<<<1, 256, 0, stream>>>(mask_raw, flag);
  pack_mask<<<dim3(S_DIM / 64, S_DIM / 64, B_DIM), 256, 0, stream>>>(mask_raw, flag, bits);
  invm_from_bits<<<(B_DIM * S_DIM) / 256, 256, 0, stream>>>(bits, invm);
  cvt_bf16<<<(3 * U_DIM * U_DIM) / 1024, 256, 0, stream>>>(w_qkv, wqkv_bf, 3 * U_DIM * U_DIM);
  cvt_bf16<<<(U_DIM * U_DIM) / 1024, 256, 0, stream>>>(w_out, wout_bf, U_DIM * U_DIM);

  for (int b0 = 0; b0 < B_DIM; b0 += nb) {
    int cnt = (B_DIM - b0 < nb) ? (B_DIM - b0) : nb;
    transpose_x<<<dim3(S_DIM / 32, U_DIM / 32, cnt), 256, 0, stream>>>(
        x + (size_t)b0 * U_DIM * S_DIM, xT);
    gemm_tt<unsigned short><<<dim3(3 * U_DIM / 128, S_DIM / 128, cnt), 256, 0, stream>>>(
        xT, wqkv_bf, qkvT, (long long)U_DIM * S_DIM, 0LL, (long long)3 * U_DIM * S_DIM, 3 * U_DIM);
    transpose_v<<<dim3(S_DIM / 32, U_DIM / 32, cnt), 256, 0, stream>>>(qkvT, VT);
    attn_mfma<<<dim3(S_DIM / 64, H_DIM, cnt), 256, 0, stream>>>(
        qkvT, VT, bits, invm, CcT, b0);
    gemm_tt<float><<<dim3(S_DIM / 128, U_DIM / 128, cnt), 256, 0, stream>>>(
        wout_bf, CcT, out + (size_t)b0 * U_DIM * S_DIM, 0LL,
        (long long)U_DIM * S_DIM, (long long)U_DIM * S_DIM, S_DIM);
  }
}